// Round 13
// baseline (229.731 us; speedup 1.0000x reference)
//
#include <hip/hip_runtime.h>

// ---------------------------------------------------------------------------
// Transformer block forward on gfx950.  B=2 T=2048 C=1024 H=16 HS=64 FF=4096.
// All matmuls: f16 inputs, fp32 MFMA accumulation (16x16x32).
// R13: gemm_ks moves to BK=64 fat iterations (32 MFMA/wave/iter, KT halved):
//      per group 2 buffers x [2 kk][128][32] subtiles (128 KB LDS), vmcnt(8)
//      + barrier -> 32 MFMA -> barrier -> stage(t+2).  Diagnosis: both GEMM
//      kernels show a fixed ~1800-1900 cyc/iteration wall independent of
//      prefetch depth; amortize it with fatter iterations (gemm8 parity).
//      Everything else frozen at R12.
// Workspace layout (80 MB): unchanged.
// ---------------------------------------------------------------------------

typedef _Float16 f16;
typedef _Float16 f16x8 __attribute__((ext_vector_type(8)));
typedef _Float16 f16x4v __attribute__((ext_vector_type(4)));
typedef float f32x4 __attribute__((ext_vector_type(4)));

static constexpr int Tn = 2048;
static constexpr int Cn = 1024;
static constexpr int HSn = 64;

// async global->LDS, 16B per lane; dest = wave-uniform base + lane*16
__device__ __forceinline__ void glds16(const f16* g, f16* l) {
    __builtin_amdgcn_global_load_lds((const __attribute__((address_space(1))) void*)g,
                                     (__attribute__((address_space(3))) void*)l,
                                     16, 0, 0);
}

#define VMCNT(N) asm volatile("s_waitcnt vmcnt(" #N ")" ::: "memory")
// raw barrier with code-motion fences (no implicit vmcnt/lgkm drain)
__device__ __forceinline__ void barrier_raw() {
    asm volatile("" ::: "memory");
    __builtin_amdgcn_s_barrier();
    asm volatile("" ::: "memory");
}

// pack two f32 -> two f16 (RTZ) as a u32 (v_cvt_pkrtz_f16_f32)
__device__ __forceinline__ unsigned cvt_pk_u32(float a, float b) {
    auto v = __builtin_amdgcn_cvt_pkrtz(a, b);
    union { __fp16 h2 __attribute__((ext_vector_type(2))); unsigned u; } c;
    c.h2 = v;
    return c.u;
}

// ---------------------------------------------------------------------------
// LayerNorm (fp32 in) -> f16 out.  One block per row, 256 threads.
// ---------------------------------------------------------------------------
__global__ __launch_bounds__(256) void ln_kernel(const float* __restrict__ x,
                                                 const float* __restrict__ w,
                                                 const float* __restrict__ b,
                                                 f16* __restrict__ out) {
    int row = blockIdx.x;
    const float* xr = x + (size_t)row * Cn;
    int tid = threadIdx.x, l = tid & 63, wv = tid >> 6;
    float4 v = *(const float4*)(xr + tid * 4);
    float s = v.x + v.y + v.z + v.w;
    float sq = v.x * v.x + v.y * v.y + v.z * v.z + v.w * v.w;
#pragma unroll
    for (int off = 32; off > 0; off >>= 1) {
        s += __shfl_down(s, off);
        sq += __shfl_down(sq, off);
    }
    __shared__ float red[8];
    if (l == 0) { red[wv] = s; red[wv + 4] = sq; }
    __syncthreads();
    float ts = red[0] + red[1] + red[2] + red[3];
    float tq = red[4] + red[5] + red[6] + red[7];
    float mean = ts * (1.0f / Cn);
    float var = tq * (1.0f / Cn) - mean * mean;
    float rstd = rsqrtf(var + 1e-5f);
    float4 wv4 = *(const float4*)(w + tid * 4);
    float4 bv4 = *(const float4*)(b + tid * 4);
    f16x4v o;
    o[0] = (f16)((v.x - mean) * rstd * wv4.x + bv4.x);
    o[1] = (f16)((v.y - mean) * rstd * wv4.y + bv4.y);
    o[2] = (f16)((v.z - mean) * rstd * wv4.z + bv4.z);
    o[3] = (f16)((v.w - mean) * rstd * wv4.w + bv4.w);
    *(f16x4v*)(out + (size_t)row * Cn + tid * 4) = o;
}

// ---------------------------------------------------------------------------
// Transpose + cast fp32 -> f16:  out[c][r] = in[r][c].  32x32 tiles.
// ---------------------------------------------------------------------------
__global__ __launch_bounds__(256) void tr_cast_f32(const float* __restrict__ in, int irs,
                                                   f16* __restrict__ out, int ors) {
    __shared__ float tile[32][33];
    int r0 = blockIdx.x * 32, c0 = blockIdx.y * 32;
    int t = threadIdx.x;
    int rr = t >> 3, c4 = (t & 7) * 4;
    float4 v = *(const float4*)(in + (size_t)(r0 + rr) * irs + c0 + c4);
    tile[rr][c4] = v.x; tile[rr][c4 + 1] = v.y; tile[rr][c4 + 2] = v.z; tile[rr][c4 + 3] = v.w;
    __syncthreads();
    int cc = t >> 3, r4 = (t & 7) * 4;
    f16x4v o;
    o[0] = (f16)tile[r4][cc];
    o[1] = (f16)tile[r4 + 1][cc];
    o[2] = (f16)tile[r4 + 2][cc];
    o[3] = (f16)tile[r4 + 3][cc];
    *(f16x4v*)(out + (size_t)(c0 + cc) * ors + r0 + r4) = o;
}

// Same, but gathers Wq/Wk/Wv [H][C][HS] into Wqkv^T rows n = qkv*1024 + h*64 + s.
__global__ __launch_bounds__(256) void tr_cast_qkv(const float* __restrict__ Wq,
                                                   const float* __restrict__ Wk,
                                                   const float* __restrict__ Wv,
                                                   f16* __restrict__ out) {
    int z = blockIdx.z;
    int qkv = z >> 4, h = z & 15;
    const float* in = (qkv == 0 ? Wq : qkv == 1 ? Wk : Wv) + (size_t)h * Cn * HSn; // [1024][64]
    f16* o = out + (size_t)(qkv * Cn + h * HSn) * Cn;
    __shared__ float tile[32][33];
    int r0 = blockIdx.x * 32, c0 = blockIdx.y * 32;
    int t = threadIdx.x;
    int rr = t >> 3, c4 = (t & 7) * 4;
    float4 v = *(const float4*)(in + (size_t)(r0 + rr) * HSn + c0 + c4);
    tile[rr][c4] = v.x; tile[rr][c4 + 1] = v.y; tile[rr][c4 + 2] = v.z; tile[rr][c4 + 3] = v.w;
    __syncthreads();
    int cc = t >> 3, r4 = (t & 7) * 4;
    f16x4v ov;
    ov[0] = (f16)tile[r4][cc];
    ov[1] = (f16)tile[r4 + 1][cc];
    ov[2] = (f16)tile[r4 + 2][cc];
    ov[3] = (f16)tile[r4 + 3][cc];
    *(f16x4v*)(o + (size_t)(c0 + cc) * Cn + r0 + r4) = ov;
}

// ---------------------------------------------------------------------------
// f16 transpose: vT[bh][s][t] = QKV[(b*T+t)][2048 + h*64 + s].  64x64 tiles.
// ---------------------------------------------------------------------------
__global__ __launch_bounds__(256) void tr_vT(const f16* __restrict__ QKV, f16* __restrict__ vT) {
    int bh = blockIdx.z;
    int b = bh >> 4, h = bh & 15;
    const f16* in = QKV + (size_t)b * Tn * 3072 + 2048 + h * HSn; // [T][64] stride 3072
    f16* out = vT + (size_t)bh * HSn * Tn;                        // [64][T]
    int r0 = blockIdx.x * 64;
    __shared__ __align__(16) f16 tile[64][72];
    int t = threadIdx.x;
#pragma unroll
    for (int i = 0; i < 2; i++) {
        int f = i * 256 + t;
        int rr = f >> 3, c8 = (f & 7) * 8;
        *(uint4*)(&tile[rr][c8]) = *(const uint4*)(in + (size_t)(r0 + rr) * 3072 + c8);
    }
    __syncthreads();
#pragma unroll
    for (int i = 0; i < 2; i++) {
        int f = i * 256 + t;
        int cc = f >> 3, r8 = (f & 7) * 8;
        union { f16 h[8]; uint4 v; } u;
#pragma unroll
        for (int j = 0; j < 8; j++) u.h[j] = tile[r8 + j][cc];
        *(uint4*)(out + (size_t)cc * Tn + r0 + r8) = u.v;
    }
}

// ---------------------------------------------------------------------------
// gemm8: C[M][N] = A[M][K] @ Bt[N][K]^T, 256x256 tile, 8 waves (2M x 4N),
// BK=32, 4 LDS buffers, stage depth 3, vmcnt(8) (tail 4/0) + s_barrier per
// K-tile, 2 phases x 16 MFMA, XOR chunk swizzle both sides, setprio.
// (QKV, FF1)
// ---------------------------------------------------------------------------
template <int EPI>
__global__ __launch_bounds__(512, 2) void gemm8(const f16* __restrict__ A, const f16* __restrict__ Bt,
                                                f16* __restrict__ Cout, int M, int N, int K) {
    __shared__ __align__(16) f16 Abuf[4][8192];
    __shared__ __align__(16) f16 Bbuf[4][8192];
    int wg = blockIdx.x;
    int xcd = wg & 7, idx = wg >> 3;
    int bm = xcd * 2 + (idx & 1), bn = idx >> 1;
    int tid = threadIdx.x, l = tid & 63, w = tid >> 6;
    int wr = w >> 2, wc = w & 3;

    f32x4 acc[8][4];
#pragma unroll
    for (int m = 0; m < 8; m++)
#pragma unroll
        for (int n = 0; n < 4; n++) acc[m][n] = f32x4{0.f, 0.f, 0.f, 0.f};

    int l15 = l & 15;
    int lane_off = l15 * 32 + (((l >> 4) ^ ((l15 >> 1) & 3)) << 3);
    const f16* Afr = &Abuf[0][wr * 4096 + lane_off];
    const f16* Bfr = &Bbuf[0][(wc >> 1) * 4096 + (wc & 1) * 2048 + lane_off];

    int srow = w * 16 + (l >> 2);
    int schunk = (l & 3) ^ ((l >> 3) & 3);
    const f16* agp = A + (size_t)(bm * 256 + srow) * K + schunk * 8;
    const f16* bgp = Bt + (size_t)(bn * 256 + srow) * K + schunk * 8;
    const size_t rK = (size_t)128 * K;
    f16* dstA = &Abuf[0][w * 512];
    f16* dstB = &Bbuf[0][w * 512];

    auto stage = [&](int kt, int bf) {
        int k0 = kt * 32;
        glds16(agp + k0, dstA + bf * 8192);
        glds16(agp + rK + k0, dstA + bf * 8192 + 4096);
        glds16(bgp + k0, dstB + bf * 8192);
        glds16(bgp + rK + k0, dstB + bf * 8192 + 4096);
    };

    int NT = K >> 5;
    stage(0, 0);
    stage(1, 1);
    stage(2, 2);
    for (int t = 0; t < NT; ++t) {
        int cb = t & 3;
        if (t < NT - 2) VMCNT(8);        // tiles t+1, t+2 stay in flight
        else if (t == NT - 2) VMCNT(4);  // only t+1 in flight
        else VMCNT(0);                   // last tile: drain
        barrier_raw();
        const f16* Ab = Afr + cb * 8192;
        const f16* Bb = Bfr + cb * 8192;
        f16x8 af[4], bf4[4];
#pragma unroll
        for (int m = 0; m < 4; m++) af[m] = *(const f16x8*)(Ab + m * 512);
#pragma unroll
        for (int n = 0; n < 4; n++) bf4[n] = *(const f16x8*)(Bb + n * 512);
        if (t + 3 < NT) stage(t + 3, (t + 3) & 3);
        __builtin_amdgcn_s_setprio(1);
#pragma unroll
        for (int m = 0; m < 4; m++)
#pragma unroll
            for (int n = 0; n < 4; n++)
                acc[m][n] = __builtin_amdgcn_mfma_f32_16x16x32_f16(af[m], bf4[n], acc[m][n], 0, 0, 0);
        __builtin_amdgcn_s_setprio(0);
        barrier_raw();
#pragma unroll
        for (int m = 0; m < 4; m++) af[m] = *(const f16x8*)(Ab + (m + 4) * 512);
        __builtin_amdgcn_s_setprio(1);
#pragma unroll
        for (int m = 0; m < 4; m++)
#pragma unroll
            for (int n = 0; n < 4; n++)
                acc[m + 4][n] = __builtin_amdgcn_mfma_f32_16x16x32_f16(af[m], bf4[n], acc[m + 4][n], 0, 0, 0);
        __builtin_amdgcn_s_setprio(0);
    }

    int row0 = bm * 256 + wr * 128 + (l >> 4) * 4;
    int col0 = bn * 256 + wc * 64 + (l & 15);
#pragma unroll
    for (int m = 0; m < 8; m++) {
#pragma unroll
        for (int n = 0; n < 4; n++) {
#pragma unroll
            for (int r = 0; r < 4; r++) {
                size_t idx = (size_t)(row0 + m * 16 + r) * N + (col0 + n * 16);
                float v = acc[m][n][r];
                if constexpr (EPI == 1) v = fmaxf(v, 0.f);
                Cout[idx] = (f16)v;
            }
        }
    }
}

// L2-aware decode for 128^2 grids: XCD x owns bm-chunk [4x, 4x+4).
__device__ __forceinline__ void l2_map(int& bm, int& bn) {
    int wg = blockIdx.y * 32 + blockIdx.x;
    int x = wg & 7, idx = wg >> 3;
    bm = x * 4 + (idx & 3);
    bn = idx >> 2;
}

// ---------------------------------------------------------------------------
// GEMM with in-block split-K, BK=64 fat iterations: 512 threads = 2 groups x
// 4 waves; group g covers K-range [g*K/2, (g+1)*K/2).  Per group: 2 buffers
// x [2 kk][128][32] subtiles (existing swizzle per subtile), 128 KB LDS
// total.  Per iter: vmcnt(8) (stages t,t+1 outstanding=16; retire t's 8) ->
// barrier -> 2x16 MFMA (kk=0,1) -> barrier (buf t&1 free) -> stage(t+2,t&1).
// Group 1 reduced into group 0 via LDS.  (proj, FF2)
// ---------------------------------------------------------------------------
template <int EPI>
__global__ __launch_bounds__(512) void gemm_ks(const f16* __restrict__ A, const f16* __restrict__ Bt,
                                               void* __restrict__ Cout, const float* __restrict__ resid,
                                               int M, int N, int K) {
    __shared__ __align__(16) char smem[131072];
    f16* As = (f16*)smem;            // [grp][2 buf][2 kk][4096] = 64KB
    f16* Bs = (f16*)(smem + 65536);  // same = 64KB
    int bm, bn;
    l2_map(bm, bn);
    int tid = threadIdx.x, l = tid & 63, w = tid >> 6;
    int grp = w >> 2, wl = w & 3;
    int wr = wl >> 1, wc = wl & 1;
    int Kh = K >> 1;
    int KT2 = Kh >> 6; // BK=64 iterations (FF2: 32, proj: 8)

    f32x4 acc[4][4];
#pragma unroll
    for (int m = 0; m < 4; m++)
#pragma unroll
        for (int n = 0; n < 4; n++) acc[m][n] = f32x4{0.f, 0.f, 0.f, 0.f};

    int schunk = (l & 3) ^ ((l >> 3) & 3);
    const f16* agp = A + (size_t)(bm * 128 + wl * 16 + (l >> 2)) * K + grp * Kh + schunk * 8;
    const f16* bgp = Bt + (size_t)(bn * 128 + wl * 16 + (l >> 2)) * K + grp * Kh + schunk * 8;
    const size_t half = (size_t)64 * K;
    f16* Ab = As + grp * 16384;
    f16* Bb = Bs + grp * 16384;

    // stage one BK=64 tile = two BK=32 subtiles (8 glds16 per wave)
    auto stage = [&](int kt, int bf) {
#pragma unroll
        for (int kk = 0; kk < 2; kk++) {
            size_t k0 = (size_t)kt * 64 + kk * 32;
            f16* d = Ab + bf * 8192 + kk * 4096 + wl * 512;
            glds16(agp + k0, d);
            glds16(agp + half + k0, d + 2048);
            f16* e = Bb + bf * 8192 + kk * 4096 + wl * 512;
            glds16(bgp + k0, e);
            glds16(bgp + half + k0, e + 2048);
        }
    };

    int l15 = l & 15;
    int rbase = (wr * 64 + l15) * 32 + (((l >> 4) ^ ((l15 >> 1) & 3)) << 3);
    int cbase = (wc * 64 + l15) * 32 + (((l >> 4) ^ ((l15 >> 1) & 3)) << 3);

    stage(0, 0);
    if (KT2 > 1) stage(1, 1);
    for (int kt = 0; kt < KT2; ++kt) {
        int cb = kt & 1;
        if (kt + 1 < KT2) VMCNT(8);  // stage kt+1's 8 loads stay in flight
        else VMCNT(0);
        barrier_raw();
#pragma unroll
        for (int kk = 0; kk < 2; kk++) {
            const f16* Abk = Ab + cb * 8192 + kk * 4096;
            const f16* Bbk = Bb + cb * 8192 + kk * 4096;
            f16x8 af[4], bfr[4];
#pragma unroll
            for (int m = 0; m < 4; m++) af[m] = *(const f16x8*)(Abk + rbase + m * 512);
#pragma unroll
            for (int n = 0; n < 4; n++) bfr[n] = *(const f16x8*)(Bbk + cbase + n * 512);
            __builtin_amdgcn_s_setprio(1);
#pragma unroll
            for (int m = 0; m < 4; m++)
#pragma unroll
                for (int n = 0; n < 4; n++)
                    acc[m][n] = __builtin_amdgcn_mfma_f32_16x16x32_f16(af[m], bfr[n], acc[m][n], 0, 0, 0);
            __builtin_amdgcn_s_setprio(0);
        }
        barrier_raw(); // all waves done reading buf cb
        if (kt + 2 < KT2) stage(kt + 2, cb); // overwrite just-consumed buffer
    }
    __syncthreads(); // full drain before reduction scratch aliases As

    float* red = (float*)smem;
#pragma unroll
    for (int m = 0; m < 4; m++) {
        if (grp == 1) {
#pragma unroll
            for (int n = 0; n < 4; n++)
                *(f32x4*)(red + wl * 1280 + l * 20 + n * 4) = acc[m][n];
        }
        __syncthreads();
        if (grp == 0) {
#pragma unroll
            for (int n = 0; n < 4; n++)
                acc[m][n] += *(const f32x4*)(red + wl * 1280 + l * 20 + n * 4);
        }
        __syncthreads();
    }

    if (grp == 0) {
        int row0 = bm * 128 + wr * 64 + (l >> 4) * 4;
        int col0 = bn * 128 + wc * 64 + (l & 15);
#pragma unroll
        for (int m = 0; m < 4; m++) {
#pragma unroll
            for (int n = 0; n < 4; n++) {
#pragma unroll
                for (int r = 0; r < 4; r++) {
                    size_t idx = (size_t)(row0 + m * 16 + r) * N + (col0 + n * 16);
                    float v = acc[m][n][r];
                    if constexpr (EPI == 0) ((f16*)Cout)[idx] = (f16)v;
                    else if constexpr (EPI == 1) ((f16*)Cout)[idx] = (f16)fmaxf(v, 0.f);
                    else ((float*)Cout)[idx] = v + resid[idx];
                }
            }
        }
    }
}

// ---------------------------------------------------------------------------
// Flash attention, causal.  One q-tile per block, grid 1024 (3 blocks/CU,
// 42KB LDS), long-blocks-first dispatch, bh grouped per XCD.  Swapped QK^T,
// exp2-domain softmax, diagonal-only mask.  T14 reg-staged K/V; per-lane
// defer-max check with the cross-lane reduce inside the rare rescale branch.
// ---------------------------------------------------------------------------
__global__ __launch_bounds__(256) void attn_kernel(const f16* __restrict__ QKV,
                                                   const f16* __restrict__ vT,
                                                   const float* __restrict__ p,
                                                   f16* __restrict__ att) {
    int i = blockIdx.x;                      // 1024 = 8 xcd x 4 bh x 32 qt
    int bh = (i & 7) * 4 + ((i >> 3) & 3);   // XCD owns 4 heads (K/V L2-fit)
    int qt = 31 - (i >> 5);                  // low idx -> large qt (long first)
    int b = bh >> 4, h = bh & 15;
    int tid = threadIdx.x, w = tid >> 6, l = tid & 63;
    float sc2 = rsqrtf(p[h]) * 1.44269504f;  // scale * log2(e)

    __shared__ __align__(16) f16 Ks[2][4096];
    __shared__ __align__(16) f16 Vs[2][4096];
    __shared__ __align__(16) f16 Ps[4][16 * 80];
    f16* Pw = &Ps[w][0];

    int srow0 = tid >> 3;
    int c0 = (tid & 7) ^ (srow0 & 7);
    const f16* Kg = QKV + (size_t)b * Tn * 3072 + 1024 + h * HSn;
    const f16* Vg = vT + (size_t)bh * HSn * Tn;
    const f16* Kg0 = Kg + (size_t)srow0 * 3072 + c0 * 8;
    const f16* Kg1 = Kg + (size_t)(srow0 + 32) * 3072 + c0 * 8;
    const f16* Vg0 = Vg + (size_t)srow0 * Tn + c0 * 8;
    const f16* Vg1 = Vg + (size_t)(srow0 + 32) * Tn + c0 * 8;
    int dl = w * 512 + l * 8; // this thread's 16B LDS slot (f16 index)

    int foff[8];
#pragma unroll
    for (int n = 0; n < 4; n++)
#pragma unroll
        for (int ks = 0; ks < 2; ks++)
            foff[n * 2 + ks] = (n * 16 + (l & 15)) * 128 +
                               (((ks * 32 + (l >> 4) * 8) * 2) ^ ((l & 7) << 4));

    int qg = qt * 64 + w * 16 + (l & 15);
    int qo = qt * 64 + w * 16 + (l >> 4) * 4;
    const f16* qptr = QKV + (size_t)(b * Tn + qg) * 3072 + h * HSn + (l >> 4) * 8;
    f16x8 qf0 = *(const f16x8*)(qptr);
    f16x8 qf1 = *(const f16x8*)(qptr + 32);
    f16 sch = (f16)sc2;
#pragma unroll
    for (int j = 0; j < 8; j++) { qf0[j] *= sch; qf1[j] *= sch; }

    f32x4 o[4];
#pragma unroll
    for (int nf = 0; nf < 4; nf++) o[nf] = f32x4{0.f, 0.f, 0.f, 0.f};
    float m_r = -1e30f, l_r = 0.f;

    int nt = qt + 1;
    uint4 kr0 = *(const uint4*)(Kg0);
    uint4 kr1 = *(const uint4*)(Kg1);
    uint4 vr0 = *(const uint4*)(Vg0);
    uint4 vr1 = *(const uint4*)(Vg1);
    *(uint4*)(&Ks[0][dl]) = kr0;
    *(uint4*)(&Ks[0][2048 + dl]) = kr1;
    *(uint4*)(&Vs[0][dl]) = vr0;
    *(uint4*)(&Vs[0][2048 + dl]) = vr1;
    __syncthreads();
    for (int t = 0; t < nt; ++t) {
        int kv0 = t * 64;
        if (t + 1 < nt) {
            size_t ko = (size_t)(kv0 + 64) * 3072;
            kr0 = *(const uint4*)(Kg0 + ko);
            kr1 = *(const uint4*)(Kg1 + ko);
            vr0 = *(const uint4*)(Vg0 + kv0 + 64);
            vr1 = *(const uint4*)(Vg1 + kv0 + 64);
        }
        const char* Kb = (const char*)&Ks[t & 1][0];
        const char* Vb = (const char*)&Vs[t & 1][0];
        f32x4 s[4];
#pragma unroll
        for (int n = 0; n < 4; n++) s[n] = f32x4{0.f, 0.f, 0.f, 0.f};
        __builtin_amdgcn_s_setprio(1);
#pragma unroll
        for (int n = 0; n < 4; n++)
#pragma unroll
            for (int ks = 0; ks < 2; ks++) {
                f16x8 kf = *(const f16x8*)(Kb + foff[n * 2 + ks]);
                s[n] = __builtin_amdgcn_mfma_f32_16x16x32_f16(kf, ks == 0 ? qf0 : qf1, s[n], 0, 0, 0);
            }
        __builtin_amdgcn_s_setprio(0);
        if (t == qt) {
            int rel = qg - kv0;
#pragma unroll
            for (int n = 0; n < 4; n++)
#pragma unroll
                for (int r = 0; r < 4; r++) {
                    int kvr = n * 16 + (l >> 4) * 4 + r;
                    if (kvr > rel) s[n][r] = -1e30f;
                }
        }
        float tmax = -1e30f;
#pragma unroll
        for (int n = 0; n < 4; n++)
#pragma unroll
            for (int r = 0; r < 4; r++) tmax = fmaxf(tmax, s[n][r]);
        float lmul = 1.f;
        if (__any(tmax > m_r + 8.f)) {
            float rmax = fmaxf(tmax, __shfl_xor(tmax, 16));
            rmax = fmaxf(rmax, __shfl_xor(rmax, 32));
            float mnew = fmaxf(m_r, rmax);
            lmul = exp2f(m_r - mnew);
            m_r = mnew;
            float ar[4];
#pragma unroll
            for (int r = 0; r < 4; r++) ar[r] = __shfl(lmul, (l >> 4) * 4 + r);
#pragma unroll
            for (int nf = 0; nf < 4; nf++)
#pragma unroll
                for (int r = 0; r < 4; r++) o[nf][r] *= ar[r];
        }
        float rsum = 0.f;
#pragma unroll
        for (int n = 0; n < 4; n++) {
            float e0 = exp2f(s[n][0] - m_r), e1 = exp2f(s[n][1] - m_r);
            float e2 = exp2f(s[n][2] - m_r), e3 = exp2f(s[n][3] - m_r);
            rsum += (e0 + e1) + (e2 + e3);
            union { unsigned u[2]; f16x4v h4; } u;
            u.u[0] = cvt_pk_u32(e0, e1);
            u.u[1] = cvt_pk_u32(e2, e3);
            *(f16x4v*)(&Pw[(l & 15) * 80 + n * 16 + (l >> 4) * 4]) = u.h4;
        }
        l_r = l_r * lmul + rsum;
        f16x8 pa0 = *(const f16x8*)(&Pw[(l & 15) * 80 + (l >> 4) * 8]);
        f16x8 pa1 = *(const f16x8*)(&Pw[(l & 15) * 80 + 32 + (l >> 4) * 8]);
        __builtin_amdgcn_s_setprio(1);
#pragma unroll
        for (int nf = 0; nf < 4; nf++)
#pragma unroll
            for (int ks = 0; ks < 2; ks++) {
                f16x8 vf = *(const f16x8*)(Vb + foff[nf * 2 + ks]);
                o[nf] = __builtin_amdgcn_mfma_f32_16x16x32_f16(ks == 0 ? pa0 : pa1, vf, o[nf], 0, 0, 0);
            }
        __builtin_amdgcn_s_setprio(0);
        if (t + 1 < nt) {
            int nbf = (t + 1) & 1;
            *(uint4*)(&Ks[nbf][dl]) = kr0;
            *(uint4*)(&Ks[nbf][2048 + dl]) = kr1;
            *(uint4*)(&Vs[nbf][dl]) = vr0;
            *(uint4*)(&Vs[nbf][2048 + dl]) = vr1;
            __syncthreads();
        }
    }
    float lsum = l_r;
    lsum += __shfl_xor(lsum, 16);
    lsum += __shfl_xor(lsum, 32);
    float lro[4];
#pragma unroll
    for (int r = 0; r < 4; r++) lro[r] = __shfl(lsum, (l >> 4) * 4 + r);
#pragma unroll
    for (int nf = 0; nf < 4; nf++) {
#pragma unroll
        for (int r = 0; r < 4; r++) {
            float v = o[nf][r] / lro[r];
            att[(size_t)(b * Tn + qo + r) * Cn + h * HSn + nf * 16 + (l & 15)] = (f16)v;
        }
    }
}

// ---------------------------------------------------------------------------
extern "C" void kernel_launch(void* const* d_in, const int* in_sizes, int n_in,
                              void* d_out, int out_size, void* d_ws, size_t ws_size,
                              hipStream_t stream) {
    const float* x = (const float*)d_in[0];
    const float* Wq = (const float*)d_in[1];
    const float* Wk = (const float*)d_in[2];
    const float* Wv = (const float*)d_in[3];
    const float* p = (const float*)d_in[4];
    const float* Wproj = (const float*)d_in[5];
    const float* W1 = (const float*)d_in[6];
    const float* W2 = (const float*)d_in[7];
    const float* ln1w = (const float*)d_in[8];
    const float* ln1b = (const float*)d_in[9];
    const float* ln2w = (const float*)d_in[10];
    const float* ln2b = (const float*)d_in[11];

    char* ws = (char*)d_ws;
    const size_t MB = 1ull << 20;
    f16* Wqkv_t = (f16*)(ws + 0 * MB);   // [3072][1024]
    f16* Wproj_t = (f16*)(ws + 6 * MB);  // [1024][1024]
    f16* W1_t = (f16*)(ws + 8 * MB);     // [4096][1024]
    f16* W2_t = (f16*)(ws + 16 * MB);    // [1024][4096]
    float* x1 = (float*)(ws + 24 * MB);  // [4096][1024] f32
    f16* QKV = (f16*)(ws + 40 * MB);     // [4096][3072]
    f16* h1 = (f16*)(ws + 64 * MB);      // [4096][1024]
    f16* vTb = (f16*)(ws + 64 * MB);     // [32][64][2048] (reuses h1 slot)
    f16* attb = (f16*)(ws + 72 * MB);    // [4096][1024]
    f16* h2 = attb;                      // reuse (att dead after proj gemm)
    f16* ffh = QKV;                      // [4096][4096] spans 40M..72M
    float* out = (float*)d_out;

    // weight repack (transposed f16)
    tr_cast_qkv<<<dim3(32, 2, 48), 256, 0, stream>>>(Wq, Wk, Wv, Wqkv_t);
    tr_cast_f32<<<dim3(32, 32), 256, 0, stream>>>(Wproj, 1024, Wproj_t, 1024);
    tr_cast_f32<<<dim3(32, 128), 256, 0, stream>>>(W1, 4096, W1_t, 1024);
    tr_cast_f32<<<dim3(128, 32), 256, 0, stream>>>(W2, 1024, W2_t, 4096);

    // block forward
    ln_kernel<<<4096, 256, 0, stream>>>(x, ln1w, ln1b, h1);
    gemm8<0><<<192, 512, 0, stream>>>(h1, Wqkv_t, QKV, 4096, 3072, 1024);
    tr_vT<<<dim3(32, 1, 32), 256, 0, stream>>>(QKV, vTb);
    attn_kernel<<<1024, 256, 0, stream>>>(QKV, vTb, p, attb);
    gemm_ks<2><<<dim3(32, 8), 512, 0, stream>>>(attb, Wproj_t, x1, x, 4096, 1024, 1024);
    ln_kernel<<<4096, 256, 0, stream>>>(x1, ln2w, ln2b, h2);
    gemm8<1><<<256, 512, 0, stream>>>(h2, W1_t, ffh, 4096, 4096, 1024);
    gemm_ks<2><<<dim3(32, 8), 512, 0, stream>>>(ffh, W2_t, out, x1, 4096, 1024, 4096);
}

// Round 15
// 228.075 us; speedup vs baseline: 1.0073x; 1.0073x over previous
//
#include <hip/hip_runtime.h>

// ---------------------------------------------------------------------------
// Transformer block forward on gfx950.  B=2 T=2048 C=1024 H=16 HS=64 FF=4096.
// All matmuls: f16 inputs, fp32 MFMA accumulation (16x16x32).
// R15 (= R14 + aliasing fix): FF2 partials are 32 MB (4 x 8 MB), which
//   clobbered x1.  Fix: x1 now lives in d_out (proj writes resid there, ln2
//   reads it, ff2_epi adds partials in place); partials at 0/8/24/32 MB.
//   R14 content otherwise unchanged: FF2 = 4-way cross-block split-K on the
//   256^2 gemm8 structure (demand 512->256 MB); attention pairs adjacent
//   q-tiles (8 waves share one K/V stream); proj on R12 gemm_ks.
// ---------------------------------------------------------------------------

typedef _Float16 f16;
typedef _Float16 f16x8 __attribute__((ext_vector_type(8)));
typedef _Float16 f16x4v __attribute__((ext_vector_type(4)));
typedef float f32x4 __attribute__((ext_vector_type(4)));

static constexpr int Tn = 2048;
static constexpr int Cn = 1024;
static constexpr int HSn = 64;

// async global->LDS, 16B per lane; dest = wave-uniform base + lane*16
__device__ __forceinline__ void glds16(const f16* g, f16* l) {
    __builtin_amdgcn_global_load_lds((const __attribute__((address_space(1))) void*)g,
                                     (__attribute__((address_space(3))) void*)l,
                                     16, 0, 0);
}

#define VMCNT(N) asm volatile("s_waitcnt vmcnt(" #N ")" ::: "memory")
// raw barrier with code-motion fences (no implicit vmcnt/lgkm drain)
__device__ __forceinline__ void barrier_raw() {
    asm volatile("" ::: "memory");
    __builtin_amdgcn_s_barrier();
    asm volatile("" ::: "memory");
}

// pack two f32 -> two f16 (RTZ) as a u32 (v_cvt_pkrtz_f16_f32)
__device__ __forceinline__ unsigned cvt_pk_u32(float a, float b) {
    auto v = __builtin_amdgcn_cvt_pkrtz(a, b);
    union { __fp16 h2 __attribute__((ext_vector_type(2))); unsigned u; } c;
    c.h2 = v;
    return c.u;
}

// ---------------------------------------------------------------------------
// LayerNorm (fp32 in) -> f16 out.  One block per row, 256 threads.
// ---------------------------------------------------------------------------
__global__ __launch_bounds__(256) void ln_kernel(const float* __restrict__ x,
                                                 const float* __restrict__ w,
                                                 const float* __restrict__ b,
                                                 f16* __restrict__ out) {
    int row = blockIdx.x;
    const float* xr = x + (size_t)row * Cn;
    int tid = threadIdx.x, l = tid & 63, wv = tid >> 6;
    float4 v = *(const float4*)(xr + tid * 4);
    float s = v.x + v.y + v.z + v.w;
    float sq = v.x * v.x + v.y * v.y + v.z * v.z + v.w * v.w;
#pragma unroll
    for (int off = 32; off > 0; off >>= 1) {
        s += __shfl_down(s, off);
        sq += __shfl_down(sq, off);
    }
    __shared__ float red[8];
    if (l == 0) { red[wv] = s; red[wv + 4] = sq; }
    __syncthreads();
    float ts = red[0] + red[1] + red[2] + red[3];
    float tq = red[4] + red[5] + red[6] + red[7];
    float mean = ts * (1.0f / Cn);
    float var = tq * (1.0f / Cn) - mean * mean;
    float rstd = rsqrtf(var + 1e-5f);
    float4 wv4 = *(const float4*)(w + tid * 4);
    float4 bv4 = *(const float4*)(b + tid * 4);
    f16x4v o;
    o[0] = (f16)((v.x - mean) * rstd * wv4.x + bv4.x);
    o[1] = (f16)((v.y - mean) * rstd * wv4.y + bv4.y);
    o[2] = (f16)((v.z - mean) * rstd * wv4.z + bv4.z);
    o[3] = (f16)((v.w - mean) * rstd * wv4.w + bv4.w);
    *(f16x4v*)(out + (size_t)row * Cn + tid * 4) = o;
}

// ---------------------------------------------------------------------------
// Transpose + cast fp32 -> f16:  out[c][r] = in[r][c].  32x32 tiles.
// ---------------------------------------------------------------------------
__global__ __launch_bounds__(256) void tr_cast_f32(const float* __restrict__ in, int irs,
                                                   f16* __restrict__ out, int ors) {
    __shared__ float tile[32][33];
    int r0 = blockIdx.x * 32, c0 = blockIdx.y * 32;
    int t = threadIdx.x;
    int rr = t >> 3, c4 = (t & 7) * 4;
    float4 v = *(const float4*)(in + (size_t)(r0 + rr) * irs + c0 + c4);
    tile[rr][c4] = v.x; tile[rr][c4 + 1] = v.y; tile[rr][c4 + 2] = v.z; tile[rr][c4 + 3] = v.w;
    __syncthreads();
    int cc = t >> 3, r4 = (t & 7) * 4;
    f16x4v o;
    o[0] = (f16)tile[r4][cc];
    o[1] = (f16)tile[r4 + 1][cc];
    o[2] = (f16)tile[r4 + 2][cc];
    o[3] = (f16)tile[r4 + 3][cc];
    *(f16x4v*)(out + (size_t)(c0 + cc) * ors + r0 + r4) = o;
}

// Same, but gathers Wq/Wk/Wv [H][C][HS] into Wqkv^T rows n = qkv*1024 + h*64 + s.
__global__ __launch_bounds__(256) void tr_cast_qkv(const float* __restrict__ Wq,
                                                   const float* __restrict__ Wk,
                                                   const float* __restrict__ Wv,
                                                   f16* __restrict__ out) {
    int z = blockIdx.z;
    int qkv = z >> 4, h = z & 15;
    const float* in = (qkv == 0 ? Wq : qkv == 1 ? Wk : Wv) + (size_t)h * Cn * HSn; // [1024][64]
    f16* o = out + (size_t)(qkv * Cn + h * HSn) * Cn;
    __shared__ float tile[32][33];
    int r0 = blockIdx.x * 32, c0 = blockIdx.y * 32;
    int t = threadIdx.x;
    int rr = t >> 3, c4 = (t & 7) * 4;
    float4 v = *(const float4*)(in + (size_t)(r0 + rr) * HSn + c0 + c4);
    tile[rr][c4] = v.x; tile[rr][c4 + 1] = v.y; tile[rr][c4 + 2] = v.z; tile[rr][c4 + 3] = v.w;
    __syncthreads();
    int cc = t >> 3, r4 = (t & 7) * 4;
    f16x4v ov;
    ov[0] = (f16)tile[r4][cc];
    ov[1] = (f16)tile[r4 + 1][cc];
    ov[2] = (f16)tile[r4 + 2][cc];
    ov[3] = (f16)tile[r4 + 3][cc];
    *(f16x4v*)(o + (size_t)(c0 + cc) * Cn + r0 + r4) = ov;
}

// ---------------------------------------------------------------------------
// f16 transpose: vT[bh][s][t] = QKV[(b*T+t)][2048 + h*64 + s].  64x64 tiles.
// ---------------------------------------------------------------------------
__global__ __launch_bounds__(256) void tr_vT(const f16* __restrict__ QKV, f16* __restrict__ vT) {
    int bh = blockIdx.z;
    int b = bh >> 4, h = bh & 15;
    const f16* in = QKV + (size_t)b * Tn * 3072 + 2048 + h * HSn; // [T][64] stride 3072
    f16* out = vT + (size_t)bh * HSn * Tn;                        // [64][T]
    int r0 = blockIdx.x * 64;
    __shared__ __align__(16) f16 tile[64][72];
    int t = threadIdx.x;
#pragma unroll
    for (int i = 0; i < 2; i++) {
        int f = i * 256 + t;
        int rr = f >> 3, c8 = (f & 7) * 8;
        *(uint4*)(&tile[rr][c8]) = *(const uint4*)(in + (size_t)(r0 + rr) * 3072 + c8);
    }
    __syncthreads();
#pragma unroll
    for (int i = 0; i < 2; i++) {
        int f = i * 256 + t;
        int cc = f >> 3, r8 = (f & 7) * 8;
        union { f16 h[8]; uint4 v; } u;
#pragma unroll
        for (int j = 0; j < 8; j++) u.h[j] = tile[r8 + j][cc];
        *(uint4*)(out + (size_t)cc * Tn + r0 + r8) = u.v;
    }
}

// ---------------------------------------------------------------------------
// gemm8: C[M][N] = A[M][K] @ Bt[N][K]^T, 256x256 tile, 8 waves (2M x 4N),
// BK=32, 4 LDS buffers, stage depth 3, vmcnt(8) (tail 4/0) + s_barrier per
// K-tile, 2 phases x 16 MFMA, XOR chunk swizzle both sides, setprio.
// (QKV, FF1)
// ---------------------------------------------------------------------------
template <int EPI>
__global__ __launch_bounds__(512, 2) void gemm8(const f16* __restrict__ A, const f16* __restrict__ Bt,
                                                f16* __restrict__ Cout, int M, int N, int K) {
    __shared__ __align__(16) f16 Abuf[4][8192];
    __shared__ __align__(16) f16 Bbuf[4][8192];
    int wg = blockIdx.x;
    int xcd = wg & 7, idx = wg >> 3;
    int bm = xcd * 2 + (idx & 1), bn = idx >> 1;
    int tid = threadIdx.x, l = tid & 63, w = tid >> 6;
    int wr = w >> 2, wc = w & 3;

    f32x4 acc[8][4];
#pragma unroll
    for (int m = 0; m < 8; m++)
#pragma unroll
        for (int n = 0; n < 4; n++) acc[m][n] = f32x4{0.f, 0.f, 0.f, 0.f};

    int l15 = l & 15;
    int lane_off = l15 * 32 + (((l >> 4) ^ ((l15 >> 1) & 3)) << 3);
    const f16* Afr = &Abuf[0][wr * 4096 + lane_off];
    const f16* Bfr = &Bbuf[0][(wc >> 1) * 4096 + (wc & 1) * 2048 + lane_off];

    int srow = w * 16 + (l >> 2);
    int schunk = (l & 3) ^ ((l >> 3) & 3);
    const f16* agp = A + (size_t)(bm * 256 + srow) * K + schunk * 8;
    const f16* bgp = Bt + (size_t)(bn * 256 + srow) * K + schunk * 8;
    const size_t rK = (size_t)128 * K;
    f16* dstA = &Abuf[0][w * 512];
    f16* dstB = &Bbuf[0][w * 512];

    auto stage = [&](int kt, int bf) {
        int k0 = kt * 32;
        glds16(agp + k0, dstA + bf * 8192);
        glds16(agp + rK + k0, dstA + bf * 8192 + 4096);
        glds16(bgp + k0, dstB + bf * 8192);
        glds16(bgp + rK + k0, dstB + bf * 8192 + 4096);
    };

    int NT = K >> 5;
    stage(0, 0);
    stage(1, 1);
    stage(2, 2);
    for (int t = 0; t < NT; ++t) {
        int cb = t & 3;
        if (t < NT - 2) VMCNT(8);
        else if (t == NT - 2) VMCNT(4);
        else VMCNT(0);
        barrier_raw();
        const f16* Ab = Afr + cb * 8192;
        const f16* Bb = Bfr + cb * 8192;
        f16x8 af[4], bf4[4];
#pragma unroll
        for (int m = 0; m < 4; m++) af[m] = *(const f16x8*)(Ab + m * 512);
#pragma unroll
        for (int n = 0; n < 4; n++) bf4[n] = *(const f16x8*)(Bb + n * 512);
        if (t + 3 < NT) stage(t + 3, (t + 3) & 3);
        __builtin_amdgcn_s_setprio(1);
#pragma unroll
        for (int m = 0; m < 4; m++)
#pragma unroll
            for (int n = 0; n < 4; n++)
                acc[m][n] = __builtin_amdgcn_mfma_f32_16x16x32_f16(af[m], bf4[n], acc[m][n], 0, 0, 0);
        __builtin_amdgcn_s_setprio(0);
        barrier_raw();
#pragma unroll
        for (int m = 0; m < 4; m++) af[m] = *(const f16x8*)(Ab + (m + 4) * 512);
        __builtin_amdgcn_s_setprio(1);
#pragma unroll
        for (int m = 0; m < 4; m++)
#pragma unroll
            for (int n = 0; n < 4; n++)
                acc[m + 4][n] = __builtin_amdgcn_mfma_f32_16x16x32_f16(af[m], bf4[n], acc[m + 4][n], 0, 0, 0);
        __builtin_amdgcn_s_setprio(0);
    }

    int row0 = bm * 256 + wr * 128 + (l >> 4) * 4;
    int col0 = bn * 256 + wc * 64 + (l & 15);
#pragma unroll
    for (int m = 0; m < 8; m++) {
#pragma unroll
        for (int n = 0; n < 4; n++) {
#pragma unroll
            for (int r = 0; r < 4; r++) {
                size_t idx = (size_t)(row0 + m * 16 + r) * N + (col0 + n * 16);
                float v = acc[m][n][r];
                if constexpr (EPI == 1) v = fmaxf(v, 0.f);
                Cout[idx] = (f16)v;
            }
        }
    }
}

// ---------------------------------------------------------------------------
// gemm8s: FF2 split-K slice on the gemm8 structure.  Block = (bm 0..15,
// bn 0..3, ks 0..3); computes 256x256 x K-slice [ks*1024,(ks+1)*1024) of
// C = ffh[4096][4096] @ W2t[1024][4096]^T into f16 partial buffer pk[ks].
// Identical pipeline to gemm8 (NT=32).
// ---------------------------------------------------------------------------
__global__ __launch_bounds__(512, 2) void gemm8s(const f16* __restrict__ A, const f16* __restrict__ Bt,
                                                 f16* __restrict__ P0, f16* __restrict__ P1,
                                                 f16* __restrict__ P2, f16* __restrict__ P3) {
    constexpr int KF = 4096; // full K (row stride of both A and Bt)
    __shared__ __align__(16) f16 Abuf[4][8192];
    __shared__ __align__(16) f16 Bbuf[4][8192];
    int wg = blockIdx.x;
    int xcd = wg & 7, idx = wg >> 3;
    int bm = xcd * 2 + (idx & 1);     // 0..15
    int r2 = idx >> 1;                // 0..15
    int bn = r2 & 3, ks = r2 >> 2;    // bn 0..3, ks 0..3
    int k0g = ks * 1024;
    int tid = threadIdx.x, l = tid & 63, w = tid >> 6;
    int wr = w >> 2, wc = w & 3;

    f32x4 acc[8][4];
#pragma unroll
    for (int m = 0; m < 8; m++)
#pragma unroll
        for (int n = 0; n < 4; n++) acc[m][n] = f32x4{0.f, 0.f, 0.f, 0.f};

    int l15 = l & 15;
    int lane_off = l15 * 32 + (((l >> 4) ^ ((l15 >> 1) & 3)) << 3);
    const f16* Afr = &Abuf[0][wr * 4096 + lane_off];
    const f16* Bfr = &Bbuf[0][(wc >> 1) * 4096 + (wc & 1) * 2048 + lane_off];

    int srow = w * 16 + (l >> 2);
    int schunk = (l & 3) ^ ((l >> 3) & 3);
    const f16* agp = A + (size_t)(bm * 256 + srow) * KF + k0g + schunk * 8;
    const f16* bgp = Bt + (size_t)(bn * 256 + srow) * KF + k0g + schunk * 8;
    const size_t rK = (size_t)128 * KF;
    f16* dstA = &Abuf[0][w * 512];
    f16* dstB = &Bbuf[0][w * 512];

    auto stage = [&](int kt, int bf) {
        int k0 = kt * 32;
        glds16(agp + k0, dstA + bf * 8192);
        glds16(agp + rK + k0, dstA + bf * 8192 + 4096);
        glds16(bgp + k0, dstB + bf * 8192);
        glds16(bgp + rK + k0, dstB + bf * 8192 + 4096);
    };

    constexpr int NT = 32;
    stage(0, 0);
    stage(1, 1);
    stage(2, 2);
    for (int t = 0; t < NT; ++t) {
        int cb = t & 3;
        if (t < NT - 2) VMCNT(8);
        else if (t == NT - 2) VMCNT(4);
        else VMCNT(0);
        barrier_raw();
        const f16* Ab = Afr + cb * 8192;
        const f16* Bb = Bfr + cb * 8192;
        f16x8 af[4], bf4[4];
#pragma unroll
        for (int m = 0; m < 4; m++) af[m] = *(const f16x8*)(Ab + m * 512);
#pragma unroll
        for (int n = 0; n < 4; n++) bf4[n] = *(const f16x8*)(Bb + n * 512);
        if (t + 3 < NT) stage(t + 3, (t + 3) & 3);
        __builtin_amdgcn_s_setprio(1);
#pragma unroll
        for (int m = 0; m < 4; m++)
#pragma unroll
            for (int n = 0; n < 4; n++)
                acc[m][n] = __builtin_amdgcn_mfma_f32_16x16x32_f16(af[m], bf4[n], acc[m][n], 0, 0, 0);
        __builtin_amdgcn_s_setprio(0);
        barrier_raw();
#pragma unroll
        for (int m = 0; m < 4; m++) af[m] = *(const f16x8*)(Ab + (m + 4) * 512);
        __builtin_amdgcn_s_setprio(1);
#pragma unroll
        for (int m = 0; m < 4; m++)
#pragma unroll
            for (int n = 0; n < 4; n++)
                acc[m + 4][n] = __builtin_amdgcn_mfma_f32_16x16x32_f16(af[m], bf4[n], acc[m + 4][n], 0, 0, 0);
        __builtin_amdgcn_s_setprio(0);
    }

    f16* P = (ks == 0) ? P0 : (ks == 1) ? P1 : (ks == 2) ? P2 : P3;
    int row0 = bm * 256 + wr * 128 + (l >> 4) * 4;
    int col0 = bn * 256 + wc * 64 + (l & 15);
#pragma unroll
    for (int m = 0; m < 8; m++) {
#pragma unroll
        for (int n = 0; n < 4; n++) {
#pragma unroll
            for (int r = 0; r < 4; r++) {
                size_t idx = (size_t)(row0 + m * 16 + r) * 1024 + (col0 + n * 16);
                P[idx] = (f16)acc[m][n][r];
            }
        }
    }
}

// FF2 epilogue: out += (p0+p1)+(p2+p3)  (out already holds resid; in-place,
// element-wise, fixed order -> deterministic)
__global__ __launch_bounds__(256) void ff2_epi(const f16* __restrict__ p0q,
                                               const f16* __restrict__ p1q,
                                               const f16* __restrict__ p2q,
                                               const f16* __restrict__ p3q,
                                               float* __restrict__ out) {
    size_t base = ((size_t)blockIdx.x * 256 + threadIdx.x) * 8;
    f16x8 p0 = *(const f16x8*)(p0q + base);
    f16x8 p1 = *(const f16x8*)(p1q + base);
    f16x8 p2 = *(const f16x8*)(p2q + base);
    f16x8 p3 = *(const f16x8*)(p3q + base);
    float4 r0 = *(const float4*)(out + base);
    float4 r1 = *(const float4*)(out + base + 4);
    float o[8];
#pragma unroll
    for (int j = 0; j < 8; j++)
        o[j] = ((float)p0[j] + (float)p1[j]) + ((float)p2[j] + (float)p3[j]);
    float4 w0 = {o[0] + r0.x, o[1] + r0.y, o[2] + r0.z, o[3] + r0.w};
    float4 w1 = {o[4] + r1.x, o[5] + r1.y, o[6] + r1.z, o[7] + r1.w};
    *(float4*)(out + base) = w0;
    *(float4*)(out + base + 4) = w1;
}

// L2-aware decode for 128^2 grids: XCD x owns bm-chunk [4x, 4x+4).
__device__ __forceinline__ void l2_map(int& bm, int& bn) {
    int wg = blockIdx.y * 32 + blockIdx.x;
    int x = wg & 7, idx = wg >> 3;
    bm = x * 4 + (idx & 3);
    bn = idx >> 2;
}

// ---------------------------------------------------------------------------
// GEMM with in-block split-K + deep pipeline (R12): 2 groups x 4 waves, per
// group 4 buffers, stage depth 3, vmcnt(8) (tail 4/0), raw barriers, XOR
// swizzle both sides.  Group 1 reduced into group 0 via LDS.  (proj)
// ---------------------------------------------------------------------------
template <int EPI>
__global__ __launch_bounds__(512) void gemm_ks(const f16* __restrict__ A, const f16* __restrict__ Bt,
                                               void* __restrict__ Cout, const float* __restrict__ resid,
                                               int M, int N, int K) {
    __shared__ __align__(16) char smem[131072];
    f16* As = (f16*)smem;            // [grp][4][4096] = 64KB
    f16* Bs = (f16*)(smem + 65536);  // [grp][4][4096] = 64KB
    int bm, bn;
    l2_map(bm, bn);
    int tid = threadIdx.x, l = tid & 63, w = tid >> 6;
    int grp = w >> 2, wl = w & 3;
    int wr = wl >> 1, wc = wl & 1;
    int Kh = K >> 1;
    int KT = Kh >> 5;

    f32x4 acc[4][4];
#pragma unroll
    for (int m = 0; m < 4; m++)
#pragma unroll
        for (int n = 0; n < 4; n++) acc[m][n] = f32x4{0.f, 0.f, 0.f, 0.f};

    int schunk = (l & 3) ^ ((l >> 3) & 3);
    const f16* agp = A + (size_t)(bm * 128 + wl * 16 + (l >> 2)) * K + grp * Kh + schunk * 8;
    const f16* bgp = Bt + (size_t)(bn * 128 + wl * 16 + (l >> 2)) * K + grp * Kh + schunk * 8;
    const size_t half = (size_t)64 * K;
    f16* Ab = As + grp * 16384;
    f16* Bb = Bs + grp * 16384;

    auto stage = [&](int kt, int bf) {
        size_t k0 = (size_t)kt * 32;
        glds16(agp + k0, Ab + bf * 4096 + wl * 512);
        glds16(agp + half + k0, Ab + bf * 4096 + 2048 + wl * 512);
        glds16(bgp + k0, Bb + bf * 4096 + wl * 512);
        glds16(bgp + half + k0, Bb + bf * 4096 + 2048 + wl * 512);
    };

    int l15 = l & 15;
    int rbase = (wr * 64 + l15) * 32 + (((l >> 4) ^ ((l15 >> 1) & 3)) << 3);
    int cbase = (wc * 64 + l15) * 32 + (((l >> 4) ^ ((l15 >> 1) & 3)) << 3);

    stage(0, 0);
    stage(1, 1);
    stage(2, 2);
    for (int kt = 0; kt < KT; ++kt) {
        int cb = kt & 3;
        if (kt < KT - 2) VMCNT(8);
        else if (kt == KT - 2) VMCNT(4);
        else VMCNT(0);
        barrier_raw();
        if (kt + 3 < KT) stage(kt + 3, (kt + 3) & 3);
        f16x8 af[4], bfr[4];
#pragma unroll
        for (int m = 0; m < 4; m++) af[m] = *(const f16x8*)(Ab + cb * 4096 + rbase + m * 512);
#pragma unroll
        for (int n = 0; n < 4; n++) bfr[n] = *(const f16x8*)(Bb + cb * 4096 + cbase + n * 512);
        __builtin_amdgcn_s_setprio(1);
#pragma unroll
        for (int m = 0; m < 4; m++)
#pragma unroll
            for (int n = 0; n < 4; n++)
                acc[m][n] = __builtin_amdgcn_mfma_f32_16x16x32_f16(af[m], bfr[n], acc[m][n], 0, 0, 0);
        __builtin_amdgcn_s_setprio(0);
    }
    __syncthreads(); // all compute done before reduction scratch aliases As

    float* red = (float*)smem;
#pragma unroll
    for (int m = 0; m < 4; m++) {
        if (grp == 1) {
#pragma unroll
            for (int n = 0; n < 4; n++)
                *(f32x4*)(red + wl * 1280 + l * 20 + n * 4) = acc[m][n];
        }
        __syncthreads();
        if (grp == 0) {
#pragma unroll
            for (int n = 0; n < 4; n++)
                acc[m][n] += *(const f32x4*)(red + wl * 1280 + l * 20 + n * 4);
        }
        __syncthreads();
    }

    if (grp == 0) {
        int row0 = bm * 128 + wr * 64 + (l >> 4) * 4;
        int col0 = bn * 128 + wc * 64 + (l & 15);
#pragma unroll
        for (int m = 0; m < 4; m++) {
#pragma unroll
            for (int n = 0; n < 4; n++) {
#pragma unroll
                for (int r = 0; r < 4; r++) {
                    size_t idx = (size_t)(row0 + m * 16 + r) * N + (col0 + n * 16);
                    float v = acc[m][n][r];
                    if constexpr (EPI == 0) ((f16*)Cout)[idx] = (f16)v;
                    else if constexpr (EPI == 1) ((f16*)Cout)[idx] = (f16)fmaxf(v, 0.f);
                    else ((float*)Cout)[idx] = v + resid[idx];
                }
            }
        }
    }
}

// ---------------------------------------------------------------------------
// Flash attention, causal.  Paired ADJACENT q-tiles: 512 threads = 8 waves =
// 2 q-tiles (lo/hi 64 rows) x 4 waves, sharing one K/V stream (staged demand
// halves).  Block covers q rows [128i,128i+128), stages KV tiles 0..2i+1; lo
// waves compute tiles <= 2i, hi waves <= 2i+1 (wave-uniform skip).  Per-wave
// algorithm: swapped QK^T, exp2 softmax, diagonal-only mask, defer-rescale,
// T14 reg-staged K/V, lane-local l.  Grid 512, long-first.  LDS 52 KB.
// ---------------------------------------------------------------------------
__global__ __launch_bounds__(512) void attn_kernel(const f16* __restrict__ QKV,
                                                   const f16* __restrict__ vT,
                                                   const float* __restrict__ p,
                                                   f16* __restrict__ att) {
    int idx = blockIdx.x;                    // 512 = 8 xcd x 4 bh x 16 pairs
    int bh = (idx & 7) * 4 + ((idx >> 3) & 3);
    int ip = 15 - (idx >> 5);                // long-first
    int b = bh >> 4, h = bh & 15;
    int tid = threadIdx.x, w = tid >> 6, l = tid & 63;
    int half = w >> 2, wl = w & 3;           // half: 0 = lo q-tile, 1 = hi
    float sc2 = rsqrtf(p[h]) * 1.44269504f;  // scale * log2(e)

    __shared__ __align__(16) f16 Ks[2][4096];
    __shared__ __align__(16) f16 Vs[2][4096];
    __shared__ __align__(16) f16 Ps[8][16 * 80];
    f16* Pw = &Ps[w][0];

    // staging: 512 threads cover [64][64] once: row = tid>>3, swizzled chunk
    int srow = tid >> 3;
    int c0 = (tid & 7) ^ (srow & 7);
    const f16* Kg = QKV + (size_t)b * Tn * 3072 + 1024 + h * HSn;
    const f16* Vg = vT + (size_t)bh * HSn * Tn;
    const f16* Kg0 = Kg + (size_t)srow * 3072 + c0 * 8;
    const f16* Vg0 = Vg + (size_t)srow * Tn + c0 * 8;
    int dl = tid * 8; // this thread's 16B LDS slot (f16 index)

    int foff[8];
#pragma unroll
    for (int n = 0; n < 4; n++)
#pragma unroll
        for (int ks = 0; ks < 2; ks++)
            foff[n * 2 + ks] = (n * 16 + (l & 15)) * 128 +
                               (((ks * 32 + (l >> 4) * 8) * 2) ^ ((l & 7) << 4));

    int qtw = 2 * ip + half;                 // this wave's diagonal tile
    int qg = ip * 128 + half * 64 + wl * 16 + (l & 15);
    int qo = ip * 128 + half * 64 + wl * 16 + (l >> 4) * 4;
    const f16* qptr = QKV + (size_t)(b * Tn + qg) * 3072 + h * HSn + (l >> 4) * 8;
    f16x8 qf0 = *(const f16x8*)(qptr);
    f16x8 qf1 = *(const f16x8*)(qptr + 32);
    f16 sch = (f16)sc2;
#pragma unroll
    for (int j = 0; j < 8; j++) { qf0[j] *= sch; qf1[j] *= sch; }

    f32x4 o[4];
#pragma unroll
    for (int nf = 0; nf < 4; nf++) o[nf] = f32x4{0.f, 0.f, 0.f, 0.f};
    float m_r = -1e30f, l_r = 0.f;

    int nt = 2 * ip + 2; // tiles staged by the block
    uint4 kr = *(const uint4*)(Kg0);
    uint4 vr = *(const uint4*)(Vg0);
    *(uint4*)(&Ks[0][dl]) = kr;
    *(uint4*)(&Vs[0][dl]) = vr;
    __syncthreads();
    for (int t = 0; t < nt; ++t) {
        int kv0 = t * 64;
        if (t + 1 < nt) { // T14: issue next tile's loads (all threads)
            kr = *(const uint4*)(Kg0 + (size_t)(kv0 + 64) * 3072);
            vr = *(const uint4*)(Vg0 + kv0 + 64);
        }
        if (t <= qtw) { // wave-uniform: lo waves skip the final staged tile
            const char* Kb = (const char*)&Ks[t & 1][0];
            const char* Vb = (const char*)&Vs[t & 1][0];
            f32x4 s[4];
#pragma unroll
            for (int n = 0; n < 4; n++) s[n] = f32x4{0.f, 0.f, 0.f, 0.f};
            __builtin_amdgcn_s_setprio(1);
#pragma unroll
            for (int n = 0; n < 4; n++)
#pragma unroll
                for (int ks = 0; ks < 2; ks++) {
                    f16x8 kf = *(const f16x8*)(Kb + foff[n * 2 + ks]);
                    s[n] = __builtin_amdgcn_mfma_f32_16x16x32_f16(kf, ks == 0 ? qf0 : qf1, s[n], 0, 0, 0);
                }
            __builtin_amdgcn_s_setprio(0);
            if (t == qtw) { // mask only on this wave's diagonal tile
                int rel = qg - kv0;
#pragma unroll
                for (int n = 0; n < 4; n++)
#pragma unroll
                    for (int r = 0; r < 4; r++) {
                        int kvr = n * 16 + (l >> 4) * 4 + r;
                        if (kvr > rel) s[n][r] = -1e30f;
                    }
            }
            float tmax = -1e30f;
#pragma unroll
            for (int n = 0; n < 4; n++)
#pragma unroll
                for (int r = 0; r < 4; r++) tmax = fmaxf(tmax, s[n][r]);
            float lmul = 1.f;
            if (__any(tmax > m_r + 8.f)) { // T13 defer-rescale (exp2 domain)
                float rmax = fmaxf(tmax, __shfl_xor(tmax, 16));
                rmax = fmaxf(rmax, __shfl_xor(rmax, 32));
                float mnew = fmaxf(m_r, rmax);
                lmul = exp2f(m_r - mnew);
                m_r = mnew;
                float ar[4];
#pragma unroll
                for (int r = 0; r < 4; r++) ar[r] = __shfl(lmul, (l >> 4) * 4 + r);
#pragma unroll
                for (int nf = 0; nf < 4; nf++)
#pragma unroll
                    for (int r = 0; r < 4; r++) o[nf][r] *= ar[r];
            }
            float rsum = 0.f;
#pragma unroll
            for (int n = 0; n < 4; n++) {
                float e0 = exp2f(s[n][0] - m_r), e1 = exp2f(s[n][1] - m_r);
                float e2 = exp2f(s[n][2] - m_r), e3 = exp2f(s[n][3] - m_r);
                rsum += (e0 + e1) + (e2 + e3);
                union { unsigned u[2]; f16x4v h4; } u;
                u.u[0] = cvt_pk_u32(e0, e1);
                u.u[1] = cvt_pk_u32(e2, e3);
                *(f16x4v*)(&Pw[(l & 15) * 80 + n * 16 + (l >> 4) * 4]) = u.h4;
            }
            l_r = l_r * lmul + rsum; // lane-local; lmul row-uniform -> exact
            f16x8 pa0 = *(const f16x8*)(&Pw[(l & 15) * 80 + (l >> 4) * 8]);
            f16x8 pa1 = *(const f16x8*)(&Pw[(l & 15) * 80 + 32 + (l >> 4) * 8]);
            __builtin_amdgcn_s_setprio(1);
#pragma unroll
            for (int nf = 0; nf < 4; nf++)
#pragma unroll
                for (int ks = 0; ks < 2; ks++) {
                    f16x8 vf = *(const f16x8*)(Vb + foff[nf * 2 + ks]);
                    o[nf] = __builtin_amdgcn_mfma_f32_16x16x32_f16(ks == 0 ? pa0 : pa1, vf, o[nf], 0, 0, 0);
                }
            __builtin_amdgcn_s_setprio(0);
        }
        if (t + 1 < nt) { // write next tile to the other buffer, fence reuse
            int nbf = (t + 1) & 1;
            *(uint4*)(&Ks[nbf][dl]) = kr;
            *(uint4*)(&Vs[nbf][dl]) = vr;
            __syncthreads();
        }
    }
    float lsum = l_r;
    lsum += __shfl_xor(lsum, 16);
    lsum += __shfl_xor(lsum, 32);
    float lro[4];
#pragma unroll
    for (int r = 0; r < 4; r++) lro[r] = __shfl(lsum, (l >> 4) * 4 + r);
#pragma unroll
    for (int nf = 0; nf < 4; nf++) {
#pragma unroll
        for (int r = 0; r < 4; r++) {
            float v = o[nf][r] / lro[r];
            att[(size_t)(b * Tn + qo + r) * Cn + h * HSn + nf * 16 + (l & 15)] = (f16)v;
        }
    }
}

// ---------------------------------------------------------------------------
extern "C" void kernel_launch(void* const* d_in, const int* in_sizes, int n_in,
                              void* d_out, int out_size, void* d_ws, size_t ws_size,
                              hipStream_t stream) {
    const float* x = (const float*)d_in[0];
    const float* Wq = (const float*)d_in[1];
    const float* Wk = (const float*)d_in[2];
    const float* Wv = (const float*)d_in[3];
    const float* p = (const float*)d_in[4];
    const float* Wproj = (const float*)d_in[5];
    const float* W1 = (const float*)d_in[6];
    const float* W2 = (const float*)d_in[7];
    const float* ln1w = (const float*)d_in[8];
    const float* ln1b = (const float*)d_in[9];
    const float* ln2w = (const float*)d_in[10];
    const float* ln2b = (const float*)d_in[11];

    char* ws = (char*)d_ws;
    const size_t MB = 1ull << 20;
    f16* Wqkv_t = (f16*)(ws + 0 * MB);   // [3072][1024]  (dead after QKV gemm)
    f16* Wproj_t = (f16*)(ws + 6 * MB);  // [1024][1024]  (dead after proj)
    f16* W1_t = (f16*)(ws + 8 * MB);     // [4096][1024]  (dead after FF1)
    f16* W2_t = (f16*)(ws + 16 * MB);    // [1024][4096]  (live through FF2)
    f16* QKV = (f16*)(ws + 40 * MB);     // [4096][3072]
    f16* h1 = (f16*)(ws + 64 * MB);      // [4096][1024]
    f16* vTb = (f16*)(ws + 64 * MB);     // [32][64][2048] (reuses h1 slot)
    f16* attb = (f16*)(ws + 72 * MB);    // [4096][1024]
    f16* h2 = attb;                      // reuse (att dead after proj gemm)
    f16* ffh = QKV;                      // [4096][4096] spans 40M..72M
    // FF2 partials: 4 x 8MB in regions dead at FF2 time
    f16* p0 = (f16*)(ws + 0 * MB);       // over Wqkv_t/Wproj_t (dead)
    f16* p1 = (f16*)(ws + 8 * MB);       // over W1_t (dead)
    f16* p2 = (f16*)(ws + 24 * MB);      // old x1 slot (now unused)
    f16* p3 = (f16*)(ws + 32 * MB);
    float* out = (float*)d_out;          // holds resid (x + sa) after proj

    // weight repack (transposed f16)
    tr_cast_qkv<<<dim3(32, 2, 48), 256, 0, stream>>>(Wq, Wk, Wv, Wqkv_t);
    tr_cast_f32<<<dim3(32, 32), 256, 0, stream>>>(Wproj, 1024, Wproj_t, 1024);
    tr_cast_f32<<<dim3(32, 128), 256, 0, stream>>>(W1, 4096, W1_t, 1024);
    tr_cast_f32<<<dim3(128, 32), 256, 0, stream>>>(W2, 1024, W2_t, 4096);

    // block forward
    ln_kernel<<<4096, 256, 0, stream>>>(x, ln1w, ln1b, h1);
    gemm8<0><<<192, 512, 0, stream>>>(h1, Wqkv_t, QKV, 4096, 3072, 1024);
    tr_vT<<<dim3(32, 1, 32), 256, 0, stream>>>(QKV, vTb);
    attn_kernel<<<512, 512, 0, stream>>>(QKV, vTb, p, attb);
    gemm_ks<2><<<dim3(32, 8), 512, 0, stream>>>(attb, Wproj_t, out, x, 4096, 1024, 1024);
    ln_kernel<<<4096, 256, 0, stream>>>(out, ln2w, ln2b, h2);
    gemm8<1><<<256, 512, 0, stream>>>(h2, W1_t, ffh, 4096, 4096, 1024);
    gemm8s<<<256, 512, 0, stream>>>(ffh, W2_t, p0, p1, p2, p3);
    ff2_epi<<<2048, 256, 0, stream>>>(p0, p1, p2, p3, out);
}

// Round 16
// 216.844 us; speedup vs baseline: 1.0594x; 1.0518x over previous
//
#include <hip/hip_runtime.h>

// ---------------------------------------------------------------------------
// Transformer block forward on gfx950.  B=2 T=2048 C=1024 H=16 HS=64 FF=4096.
// All matmuls: f16 inputs, fp32 MFMA accumulation (16x16x32).
// R16 = revert to best-measured config (R10, 216.8 us):
//   - gemm8 (QKV, FF1): 256^2 tile, 8 waves, 4 LDS buffers, depth 3,
//     vmcnt(8)+raw barrier per K-tile, XOR swizzle, setprio.
//   - gemm_ks (proj, FF2): in-block split-K, 3 buffers, depth 2, vmcnt(4).
//   - attn: 1 q-tile/block, grid 1024 long-first, T14 reg-staged K/V,
//     swapped QK^T, exp2 softmax, diagonal-only mask, per-lane defer-max.
//   R11-R15 experiments (direct-B, depth-3, BK=64, cross-block split-K,
//   q-tile pairing) were null or negative and are dropped.
// ---------------------------------------------------------------------------

typedef _Float16 f16;
typedef _Float16 f16x8 __attribute__((ext_vector_type(8)));
typedef _Float16 f16x4v __attribute__((ext_vector_type(4)));
typedef float f32x4 __attribute__((ext_vector_type(4)));

static constexpr int Tn = 2048;
static constexpr int Cn = 1024;
static constexpr int HSn = 64;

// async global->LDS, 16B per lane; dest = wave-uniform base + lane*16
__device__ __forceinline__ void glds16(const f16* g, f16* l) {
    __builtin_amdgcn_global_load_lds((const __attribute__((address_space(1))) void*)g,
                                     (__attribute__((address_space(3))) void*)l,
                                     16, 0, 0);
}

#define VMCNT(N) asm volatile("s_waitcnt vmcnt(" #N ")" ::: "memory")
// raw barrier with code-motion fences (no implicit vmcnt/lgkm drain)
__device__ __forceinline__ void barrier_raw() {
    asm volatile("" ::: "memory");
    __builtin_amdgcn_s_barrier();
    asm volatile("" ::: "memory");
}

// pack two f32 -> two f16 (RTZ) as a u32 (v_cvt_pkrtz_f16_f32)
__device__ __forceinline__ unsigned cvt_pk_u32(float a, float b) {
    auto v = __builtin_amdgcn_cvt_pkrtz(a, b);
    union { __fp16 h2 __attribute__((ext_vector_type(2))); unsigned u; } c;
    c.h2 = v;
    return c.u;
}

// ---------------------------------------------------------------------------
// LayerNorm (fp32 in) -> f16 out.  One block per row, 256 threads.
// ---------------------------------------------------------------------------
__global__ __launch_bounds__(256) void ln_kernel(const float* __restrict__ x,
                                                 const float* __restrict__ w,
                                                 const float* __restrict__ b,
                                                 f16* __restrict__ out) {
    int row = blockIdx.x;
    const float* xr = x + (size_t)row * Cn;
    int tid = threadIdx.x, l = tid & 63, wv = tid >> 6;
    float4 v = *(const float4*)(xr + tid * 4);
    float s = v.x + v.y + v.z + v.w;
    float sq = v.x * v.x + v.y * v.y + v.z * v.z + v.w * v.w;
#pragma unroll
    for (int off = 32; off > 0; off >>= 1) {
        s += __shfl_down(s, off);
        sq += __shfl_down(sq, off);
    }
    __shared__ float red[8];
    if (l == 0) { red[wv] = s; red[wv + 4] = sq; }
    __syncthreads();
    float ts = red[0] + red[1] + red[2] + red[3];
    float tq = red[4] + red[5] + red[6] + red[7];
    float mean = ts * (1.0f / Cn);
    float var = tq * (1.0f / Cn) - mean * mean;
    float rstd = rsqrtf(var + 1e-5f);
    float4 wv4 = *(const float4*)(w + tid * 4);
    float4 bv4 = *(const float4*)(b + tid * 4);
    f16x4v o;
    o[0] = (f16)((v.x - mean) * rstd * wv4.x + bv4.x);
    o[1] = (f16)((v.y - mean) * rstd * wv4.y + bv4.y);
    o[2] = (f16)((v.z - mean) * rstd * wv4.z + bv4.z);
    o[3] = (f16)((v.w - mean) * rstd * wv4.w + bv4.w);
    *(f16x4v*)(out + (size_t)row * Cn + tid * 4) = o;
}

// ---------------------------------------------------------------------------
// Transpose + cast fp32 -> f16:  out[c][r] = in[r][c].  32x32 tiles.
// ---------------------------------------------------------------------------
__global__ __launch_bounds__(256) void tr_cast_f32(const float* __restrict__ in, int irs,
                                                   f16* __restrict__ out, int ors) {
    __shared__ float tile[32][33];
    int r0 = blockIdx.x * 32, c0 = blockIdx.y * 32;
    int t = threadIdx.x;
    int rr = t >> 3, c4 = (t & 7) * 4;
    float4 v = *(const float4*)(in + (size_t)(r0 + rr) * irs + c0 + c4);
    tile[rr][c4] = v.x; tile[rr][c4 + 1] = v.y; tile[rr][c4 + 2] = v.z; tile[rr][c4 + 3] = v.w;
    __syncthreads();
    int cc = t >> 3, r4 = (t & 7) * 4;
    f16x4v o;
    o[0] = (f16)tile[r4][cc];
    o[1] = (f16)tile[r4 + 1][cc];
    o[2] = (f16)tile[r4 + 2][cc];
    o[3] = (f16)tile[r4 + 3][cc];
    *(f16x4v*)(out + (size_t)(c0 + cc) * ors + r0 + r4) = o;
}

// Same, but gathers Wq/Wk/Wv [H][C][HS] into Wqkv^T rows n = qkv*1024 + h*64 + s.
__global__ __launch_bounds__(256) void tr_cast_qkv(const float* __restrict__ Wq,
                                                   const float* __restrict__ Wk,
                                                   const float* __restrict__ Wv,
                                                   f16* __restrict__ out) {
    int z = blockIdx.z;
    int qkv = z >> 4, h = z & 15;
    const float* in = (qkv == 0 ? Wq : qkv == 1 ? Wk : Wv) + (size_t)h * Cn * HSn; // [1024][64]
    f16* o = out + (size_t)(qkv * Cn + h * HSn) * Cn;
    __shared__ float tile[32][33];
    int r0 = blockIdx.x * 32, c0 = blockIdx.y * 32;
    int t = threadIdx.x;
    int rr = t >> 3, c4 = (t & 7) * 4;
    float4 v = *(const float4*)(in + (size_t)(r0 + rr) * HSn + c0 + c4);
    tile[rr][c4] = v.x; tile[rr][c4 + 1] = v.y; tile[rr][c4 + 2] = v.z; tile[rr][c4 + 3] = v.w;
    __syncthreads();
    int cc = t >> 3, r4 = (t & 7) * 4;
    f16x4v ov;
    ov[0] = (f16)tile[r4][cc];
    ov[1] = (f16)tile[r4 + 1][cc];
    ov[2] = (f16)tile[r4 + 2][cc];
    ov[3] = (f16)tile[r4 + 3][cc];
    *(f16x4v*)(o + (size_t)(c0 + cc) * Cn + r0 + r4) = ov;
}

// ---------------------------------------------------------------------------
// f16 transpose: vT[bh][s][t] = QKV[(b*T+t)][2048 + h*64 + s].  64x64 tiles.
// ---------------------------------------------------------------------------
__global__ __launch_bounds__(256) void tr_vT(const f16* __restrict__ QKV, f16* __restrict__ vT) {
    int bh = blockIdx.z;
    int b = bh >> 4, h = bh & 15;
    const f16* in = QKV + (size_t)b * Tn * 3072 + 2048 + h * HSn; // [T][64] stride 3072
    f16* out = vT + (size_t)bh * HSn * Tn;                        // [64][T]
    int r0 = blockIdx.x * 64;
    __shared__ __align__(16) f16 tile[64][72];
    int t = threadIdx.x;
#pragma unroll
    for (int i = 0; i < 2; i++) {
        int f = i * 256 + t;
        int rr = f >> 3, c8 = (f & 7) * 8;
        *(uint4*)(&tile[rr][c8]) = *(const uint4*)(in + (size_t)(r0 + rr) * 3072 + c8);
    }
    __syncthreads();
#pragma unroll
    for (int i = 0; i < 2; i++) {
        int f = i * 256 + t;
        int cc = f >> 3, r8 = (f & 7) * 8;
        union { f16 h[8]; uint4 v; } u;
#pragma unroll
        for (int j = 0; j < 8; j++) u.h[j] = tile[r8 + j][cc];
        *(uint4*)(out + (size_t)cc * Tn + r0 + r8) = u.v;
    }
}

// ---------------------------------------------------------------------------
// gemm8: C[M][N] = A[M][K] @ Bt[N][K]^T, 256x256 tile, 8 waves (2M x 4N),
// BK=32, 4 LDS buffers, stage depth 3, vmcnt(8)+s_barrier per K-tile,
// 2 phases x 16 MFMA, XOR chunk swizzle both sides, setprio.  (QKV, FF1)
// ---------------------------------------------------------------------------
template <int EPI>
__global__ __launch_bounds__(512, 2) void gemm8(const f16* __restrict__ A, const f16* __restrict__ Bt,
                                                f16* __restrict__ Cout, int M, int N, int K) {
    __shared__ __align__(16) f16 Abuf[4][8192];
    __shared__ __align__(16) f16 Bbuf[4][8192];
    int wg = blockIdx.x;
    int xcd = wg & 7, idx = wg >> 3;
    int bm = xcd * 2 + (idx & 1), bn = idx >> 1;
    int tid = threadIdx.x, l = tid & 63, w = tid >> 6;
    int wr = w >> 2, wc = w & 3;

    f32x4 acc[8][4];
#pragma unroll
    for (int m = 0; m < 8; m++)
#pragma unroll
        for (int n = 0; n < 4; n++) acc[m][n] = f32x4{0.f, 0.f, 0.f, 0.f};

    int l15 = l & 15;
    int lane_off = l15 * 32 + (((l >> 4) ^ ((l15 >> 1) & 3)) << 3);
    const f16* Afr = &Abuf[0][wr * 4096 + lane_off];
    const f16* Bfr = &Bbuf[0][(wc >> 1) * 4096 + (wc & 1) * 2048 + lane_off];

    int srow = w * 16 + (l >> 2);
    int schunk = (l & 3) ^ ((l >> 3) & 3);
    const f16* agp = A + (size_t)(bm * 256 + srow) * K + schunk * 8;
    const f16* bgp = Bt + (size_t)(bn * 256 + srow) * K + schunk * 8;
    const size_t rK = (size_t)128 * K;
    f16* dstA = &Abuf[0][w * 512];
    f16* dstB = &Bbuf[0][w * 512];

    auto stage = [&](int kt, int bf) {
        int k0 = kt * 32;
        glds16(agp + k0, dstA + bf * 8192);
        glds16(agp + rK + k0, dstA + bf * 8192 + 4096);
        glds16(bgp + k0, dstB + bf * 8192);
        glds16(bgp + rK + k0, dstB + bf * 8192 + 4096);
    };

    int NT = K >> 5;
    stage(0, 0);
    stage(1, 1);
    stage(2, 2);
    for (int t = 0; t < NT; ++t) {
        int cb = t & 3;
        VMCNT(8);
        barrier_raw();
        const f16* Ab = Afr + cb * 8192;
        const f16* Bb = Bfr + cb * 8192;
        f16x8 af[4], bf4[4];
#pragma unroll
        for (int m = 0; m < 4; m++) af[m] = *(const f16x8*)(Ab + m * 512);
#pragma unroll
        for (int n = 0; n < 4; n++) bf4[n] = *(const f16x8*)(Bb + n * 512);
        if (t + 3 < NT) stage(t + 3, (t + 3) & 3);
        __builtin_amdgcn_s_setprio(1);
#pragma unroll
        for (int m = 0; m < 4; m++)
#pragma unroll
            for (int n = 0; n < 4; n++)
                acc[m][n] = __builtin_amdgcn_mfma_f32_16x16x32_f16(af[m], bf4[n], acc[m][n], 0, 0, 0);
        __builtin_amdgcn_s_setprio(0);
        barrier_raw();
#pragma unroll
        for (int m = 0; m < 4; m++) af[m] = *(const f16x8*)(Ab + (m + 4) * 512);
        __builtin_amdgcn_s_setprio(1);
#pragma unroll
        for (int m = 0; m < 4; m++)
#pragma unroll
            for (int n = 0; n < 4; n++)
                acc[m + 4][n] = __builtin_amdgcn_mfma_f32_16x16x32_f16(af[m], bf4[n], acc[m + 4][n], 0, 0, 0);
        __builtin_amdgcn_s_setprio(0);
    }
    VMCNT(0);

    int row0 = bm * 256 + wr * 128 + (l >> 4) * 4;
    int col0 = bn * 256 + wc * 64 + (l & 15);
#pragma unroll
    for (int m = 0; m < 8; m++) {
#pragma unroll
        for (int n = 0; n < 4; n++) {
#pragma unroll
            for (int r = 0; r < 4; r++) {
                size_t idx = (size_t)(row0 + m * 16 + r) * N + (col0 + n * 16);
                float v = acc[m][n][r];
                if constexpr (EPI == 1) v = fmaxf(v, 0.f);
                Cout[idx] = (f16)v;
            }
        }
    }
}

// L2-aware decode for 128^2 grids: XCD x owns bm-chunk [4x, 4x+4).
__device__ __forceinline__ void l2_map(int& bm, int& bn) {
    int wg = blockIdx.y * 32 + blockIdx.x;
    int x = wg & 7, idx = wg >> 3;
    bm = x * 4 + (idx & 3);
    bn = idx >> 2;
}

// ---------------------------------------------------------------------------
// GEMM with in-block split-K + deep pipeline (3 buffers, vmcnt(4), raw
// barriers, XOR swizzle both sides).  Group 1 reduced into group 0 via LDS.
// (proj, FF2)
// ---------------------------------------------------------------------------
template <int EPI>
__global__ __launch_bounds__(512) void gemm_ks(const f16* __restrict__ A, const f16* __restrict__ Bt,
                                               void* __restrict__ Cout, const float* __restrict__ resid,
                                               int M, int N, int K) {
    __shared__ __align__(16) char smem[98304];
    f16* As = (f16*)smem;            // [grp][3][4096] = 48KB
    f16* Bs = (f16*)(smem + 49152);  // [grp][3][4096] = 48KB
    int bm, bn;
    l2_map(bm, bn);
    int tid = threadIdx.x, l = tid & 63, w = tid >> 6;
    int grp = w >> 2, wl = w & 3;
    int wr = wl >> 1, wc = wl & 1;
    int Kh = K >> 1;
    int KT = Kh >> 5;

    f32x4 acc[4][4];
#pragma unroll
    for (int m = 0; m < 4; m++)
#pragma unroll
        for (int n = 0; n < 4; n++) acc[m][n] = f32x4{0.f, 0.f, 0.f, 0.f};

    int schunk = (l & 3) ^ ((l >> 3) & 3);
    const f16* agp = A + (size_t)(bm * 128 + wl * 16 + (l >> 2)) * K + grp * Kh + schunk * 8;
    const f16* bgp = Bt + (size_t)(bn * 128 + wl * 16 + (l >> 2)) * K + grp * Kh + schunk * 8;
    const size_t half = (size_t)64 * K;
    f16* Ab = As + grp * 12288;
    f16* Bb = Bs + grp * 12288;

    auto stage = [&](int kt, int bf) {
        size_t k0 = (size_t)kt * 32;
        glds16(agp + k0, Ab + bf * 4096 + wl * 512);
        glds16(agp + half + k0, Ab + bf * 4096 + 2048 + wl * 512);
        glds16(bgp + k0, Bb + bf * 4096 + wl * 512);
        glds16(bgp + half + k0, Bb + bf * 4096 + 2048 + wl * 512);
    };

    int l15 = l & 15;
    int rbase = (wr * 64 + l15) * 32 + (((l >> 4) ^ ((l15 >> 1) & 3)) << 3);
    int cbase = (wc * 64 + l15) * 32 + (((l >> 4) ^ ((l15 >> 1) & 3)) << 3);

    stage(0, 0);
    if (KT > 1) stage(1, 1);
    int nb = 2;
    for (int kt = 0; kt < KT; ++kt) {
        int cb = kt % 3;
        if (kt + 1 < KT) VMCNT(4);
        else VMCNT(0);
        barrier_raw();
        if (kt + 2 < KT) { stage(kt + 2, nb); nb = (nb == 2) ? 0 : nb + 1; }
        f16x8 af[4], bfr[4];
#pragma unroll
        for (int m = 0; m < 4; m++) af[m] = *(const f16x8*)(Ab + cb * 4096 + rbase + m * 512);
#pragma unroll
        for (int n = 0; n < 4; n++) bfr[n] = *(const f16x8*)(Bb + cb * 4096 + cbase + n * 512);
        __builtin_amdgcn_s_setprio(1);
#pragma unroll
        for (int m = 0; m < 4; m++)
#pragma unroll
            for (int n = 0; n < 4; n++)
                acc[m][n] = __builtin_amdgcn_mfma_f32_16x16x32_f16(af[m], bfr[n], acc[m][n], 0, 0, 0);
        __builtin_amdgcn_s_setprio(0);
    }
    __syncthreads(); // all compute done (drains lgkm/vm) before red aliases As

    float* red = (float*)smem;
#pragma unroll
    for (int m = 0; m < 4; m++) {
        if (grp == 1) {
#pragma unroll
            for (int n = 0; n < 4; n++)
                *(f32x4*)(red + wl * 1280 + l * 20 + n * 4) = acc[m][n];
        }
        __syncthreads();
        if (grp == 0) {
#pragma unroll
            for (int n = 0; n < 4; n++)
                acc[m][n] += *(const f32x4*)(red + wl * 1280 + l * 20 + n * 4);
        }
        __syncthreads();
    }

    if (grp == 0) {
        int row0 = bm * 128 + wr * 64 + (l >> 4) * 4;
        int col0 = bn * 128 + wc * 64 + (l & 15);
#pragma unroll
        for (int m = 0; m < 4; m++) {
#pragma unroll
            for (int n = 0; n < 4; n++) {
#pragma unroll
                for (int r = 0; r < 4; r++) {
                    size_t idx = (size_t)(row0 + m * 16 + r) * N + (col0 + n * 16);
                    float v = acc[m][n][r];
                    if constexpr (EPI == 0) ((f16*)Cout)[idx] = (f16)v;
                    else if constexpr (EPI == 1) ((f16*)Cout)[idx] = (f16)fmaxf(v, 0.f);
                    else ((float*)Cout)[idx] = v + resid[idx];
                }
            }
        }
    }
}

// ---------------------------------------------------------------------------
// Flash attention, causal.  One q-tile per block, grid 1024 (3 blocks/CU,
// 42KB LDS), long-blocks-first dispatch, bh grouped per XCD.  Swapped QK^T,
// exp2-domain softmax, diagonal-only mask.  T14 reg-staged K/V; per-lane
// defer-max check with the cross-lane reduce inside the rare rescale branch.
// ---------------------------------------------------------------------------
__global__ __launch_bounds__(256) void attn_kernel(const f16* __restrict__ QKV,
                                                   const f16* __restrict__ vT,
                                                   const float* __restrict__ p,
                                                   f16* __restrict__ att) {
    int i = blockIdx.x;                      // 1024 = 8 xcd x 4 bh x 32 qt
    int bh = (i & 7) * 4 + ((i >> 3) & 3);   // XCD owns 4 heads (K/V L2-fit)
    int qt = 31 - (i >> 5);                  // low idx -> large qt (long first)
    int b = bh >> 4, h = bh & 15;
    int tid = threadIdx.x, w = tid >> 6, l = tid & 63;
    float sc2 = rsqrtf(p[h]) * 1.44269504f;  // scale * log2(e)

    __shared__ __align__(16) f16 Ks[2][4096];
    __shared__ __align__(16) f16 Vs[2][4096];
    __shared__ __align__(16) f16 Ps[4][16 * 80];
    f16* Pw = &Ps[w][0];

    int srow0 = tid >> 3;
    int c0 = (tid & 7) ^ (srow0 & 7);
    const f16* Kg = QKV + (size_t)b * Tn * 3072 + 1024 + h * HSn;
    const f16* Vg = vT + (size_t)bh * HSn * Tn;
    const f16* Kg0 = Kg + (size_t)srow0 * 3072 + c0 * 8;
    const f16* Kg1 = Kg + (size_t)(srow0 + 32) * 3072 + c0 * 8;
    const f16* Vg0 = Vg + (size_t)srow0 * Tn + c0 * 8;
    const f16* Vg1 = Vg + (size_t)(srow0 + 32) * Tn + c0 * 8;
    int dl = w * 512 + l * 8; // this thread's 16B LDS slot (f16 index)

    int foff[8];
#pragma unroll
    for (int n = 0; n < 4; n++)
#pragma unroll
        for (int ks = 0; ks < 2; ks++)
            foff[n * 2 + ks] = (n * 16 + (l & 15)) * 128 +
                               (((ks * 32 + (l >> 4) * 8) * 2) ^ ((l & 7) << 4));

    int qg = qt * 64 + w * 16 + (l & 15);
    int qo = qt * 64 + w * 16 + (l >> 4) * 4;
    const f16* qptr = QKV + (size_t)(b * Tn + qg) * 3072 + h * HSn + (l >> 4) * 8;
    f16x8 qf0 = *(const f16x8*)(qptr);
    f16x8 qf1 = *(const f16x8*)(qptr + 32);
    f16 sch = (f16)sc2;
#pragma unroll
    for (int j = 0; j < 8; j++) { qf0[j] *= sch; qf1[j] *= sch; }

    f32x4 o[4];
#pragma unroll
    for (int nf = 0; nf < 4; nf++) o[nf] = f32x4{0.f, 0.f, 0.f, 0.f};
    float m_r = -1e30f, l_r = 0.f; // lane-local l partial (reduced at end)

    int nt = qt + 1;
    uint4 kr0 = *(const uint4*)(Kg0);
    uint4 kr1 = *(const uint4*)(Kg1);
    uint4 vr0 = *(const uint4*)(Vg0);
    uint4 vr1 = *(const uint4*)(Vg1);
    *(uint4*)(&Ks[0][dl]) = kr0;
    *(uint4*)(&Ks[0][2048 + dl]) = kr1;
    *(uint4*)(&Vs[0][dl]) = vr0;
    *(uint4*)(&Vs[0][2048 + dl]) = vr1;
    __syncthreads();
    for (int t = 0; t < nt; ++t) {
        int kv0 = t * 64;
        if (t + 1 < nt) { // T14: issue next tile's loads; consumed at tile end
            size_t ko = (size_t)(kv0 + 64) * 3072;
            kr0 = *(const uint4*)(Kg0 + ko);
            kr1 = *(const uint4*)(Kg1 + ko);
            vr0 = *(const uint4*)(Vg0 + kv0 + 64);
            vr1 = *(const uint4*)(Vg1 + kv0 + 64);
        }
        const char* Kb = (const char*)&Ks[t & 1][0];
        const char* Vb = (const char*)&Vs[t & 1][0];
        f32x4 s[4];
#pragma unroll
        for (int n = 0; n < 4; n++) s[n] = f32x4{0.f, 0.f, 0.f, 0.f};
        __builtin_amdgcn_s_setprio(1);
#pragma unroll
        for (int n = 0; n < 4; n++)
#pragma unroll
            for (int ks = 0; ks < 2; ks++) {
                f16x8 kf = *(const f16x8*)(Kb + foff[n * 2 + ks]);
                s[n] = __builtin_amdgcn_mfma_f32_16x16x32_f16(kf, ks == 0 ? qf0 : qf1, s[n], 0, 0, 0);
            }
        __builtin_amdgcn_s_setprio(0);
        if (t == qt) { // mask only on the diagonal tile
            int rel = qg - kv0;
#pragma unroll
            for (int n = 0; n < 4; n++)
#pragma unroll
                for (int r = 0; r < 4; r++) {
                    int kvr = n * 16 + (l >> 4) * 4 + r;
                    if (kvr > rel) s[n][r] = -1e30f;
                }
        }
        // per-lane partial max; full row reduce only inside the rare branch
        float tmax = -1e30f;
#pragma unroll
        for (int n = 0; n < 4; n++)
#pragma unroll
            for (int r = 0; r < 4; r++) tmax = fmaxf(tmax, s[n][r]);
        float lmul = 1.f;
        if (__any(tmax > m_r + 8.f)) { // T13 defer-rescale (exp2 domain)
            float rmax = fmaxf(tmax, __shfl_xor(tmax, 16));
            rmax = fmaxf(rmax, __shfl_xor(rmax, 32));
            float mnew = fmaxf(m_r, rmax);
            lmul = exp2f(m_r - mnew);
            m_r = mnew;
            float ar[4];
#pragma unroll
            for (int r = 0; r < 4; r++) ar[r] = __shfl(lmul, (l >> 4) * 4 + r);
#pragma unroll
            for (int nf = 0; nf < 4; nf++)
#pragma unroll
                for (int r = 0; r < 4; r++) o[nf][r] *= ar[r];
        }
        float rsum = 0.f;
#pragma unroll
        for (int n = 0; n < 4; n++) {
            float e0 = exp2f(s[n][0] - m_r), e1 = exp2f(s[n][1] - m_r);
            float e2 = exp2f(s[n][2] - m_r), e3 = exp2f(s[n][3] - m_r);
            rsum += (e0 + e1) + (e2 + e3);
            union { unsigned u[2]; f16x4v h4; } u;
            u.u[0] = cvt_pk_u32(e0, e1);
            u.u[1] = cvt_pk_u32(e2, e3);
            *(f16x4v*)(&Pw[(l & 15) * 80 + n * 16 + (l >> 4) * 4]) = u.h4;
        }
        l_r = l_r * lmul + rsum; // lane-local; lmul is row-uniform -> exact
        f16x8 pa0 = *(const f16x8*)(&Pw[(l & 15) * 80 + (l >> 4) * 8]);
        f16x8 pa1 = *(const f16x8*)(&Pw[(l & 15) * 80 + 32 + (l >> 4) * 8]);
        __builtin_amdgcn_s_setprio(1);
#pragma unroll
        for (int nf = 0; nf < 4; nf++)
#pragma unroll
            for (int ks = 0; ks < 2; ks++) {
                f16x8 vf = *(const f16x8*)(Vb + foff[nf * 2 + ks]);
                o[nf] = __builtin_amdgcn_mfma_f32_16x16x32_f16(ks == 0 ? pa0 : pa1, vf, o[nf], 0, 0, 0);
            }
        __builtin_amdgcn_s_setprio(0);
        if (t + 1 < nt) { // write next tile to the other buffer (T14 late half)
            int nbf = (t + 1) & 1;
            *(uint4*)(&Ks[nbf][dl]) = kr0;
            *(uint4*)(&Ks[nbf][2048 + dl]) = kr1;
            *(uint4*)(&Vs[nbf][dl]) = vr0;
            *(uint4*)(&Vs[nbf][2048 + dl]) = vr1;
            __syncthreads(); // writes visible; also fences buf[t&1] reuse
        }
    }
    // deferred l reduce (row sum across the 4 lane-groups), then broadcast
    float lsum = l_r;
    lsum += __shfl_xor(lsum, 16);
    lsum += __shfl_xor(lsum, 32);
    float lro[4];
#pragma unroll
    for (int r = 0; r < 4; r++) lro[r] = __shfl(lsum, (l >> 4) * 4 + r);
#pragma unroll
    for (int nf = 0; nf < 4; nf++) {
#pragma unroll
        for (int r = 0; r < 4; r++) {
            float v = o[nf][r] / lro[r];
            att[(size_t)(b * Tn + qo + r) * Cn + h * HSn + nf * 16 + (l & 15)] = (f16)v;
        }
    }
}

// ---------------------------------------------------------------------------
extern "C" void kernel_launch(void* const* d_in, const int* in_sizes, int n_in,
                              void* d_out, int out_size, void* d_ws, size_t ws_size,
                              hipStream_t stream) {
    const float* x = (const float*)d_in[0];
    const float* Wq = (const float*)d_in[1];
    const float* Wk = (const float*)d_in[2];
    const float* Wv = (const float*)d_in[3];
    const float* p = (const float*)d_in[4];
    const float* Wproj = (const float*)d_in[5];
    const float* W1 = (const float*)d_in[6];
    const float* W2 = (const float*)d_in[7];
    const float* ln1w = (const float*)d_in[8];
    const float* ln1b = (const float*)d_in[9];
    const float* ln2w = (const float*)d_in[10];
    const float* ln2b = (const float*)d_in[11];

    char* ws = (char*)d_ws;
    const size_t MB = 1ull << 20;
    f16* Wqkv_t = (f16*)(ws + 0 * MB);   // [3072][1024]
    f16* Wproj_t = (f16*)(ws + 6 * MB);  // [1024][1024]
    f16* W1_t = (f16*)(ws + 8 * MB);     // [4096][1024]
    f16* W2_t = (f16*)(ws + 16 * MB);    // [1024][4096]
    float* x1 = (float*)(ws + 24 * MB);  // [4096][1024] f32
    f16* QKV = (f16*)(ws + 40 * MB);     // [4096][3072]
    f16* h1 = (f16*)(ws + 64 * MB);      // [4096][1024]
    f16* vTb = (f16*)(ws + 64 * MB);     // [32][64][2048] (reuses h1 slot)
    f16* attb = (f16*)(ws + 72 * MB);    // [4096][1024]
    f16* h2 = attb;                      // reuse (att dead after proj gemm)
    f16* ffh = QKV;                      // [4096][4096] spans 40M..72M
    float* out = (float*)d_out;

    // weight repack (transposed f16)
    tr_cast_qkv<<<dim3(32, 2, 48), 256, 0, stream>>>(Wq, Wk, Wv, Wqkv_t);
    tr_cast_f32<<<dim3(32, 32), 256, 0, stream>>>(Wproj, 1024, Wproj_t, 1024);
    tr_cast_f32<<<dim3(32, 128), 256, 0, stream>>>(W1, 4096, W1_t, 1024);
    tr_cast_f32<<<dim3(128, 32), 256, 0, stream>>>(W2, 1024, W2_t, 4096);

    // block forward
    ln_kernel<<<4096, 256, 0, stream>>>(x, ln1w, ln1b, h1);
    gemm8<0><<<192, 512, 0, stream>>>(h1, Wqkv_t, QKV, 4096, 3072, 1024);
    tr_vT<<<dim3(32, 1, 32), 256, 0, stream>>>(QKV, vTb);
    attn_kernel<<<1024, 256, 0, stream>>>(QKV, vTb, p, attb);
    gemm_ks<2><<<dim3(32, 8), 512, 0, stream>>>(attb, Wproj_t, x1, x, 4096, 1024, 1024);
    ln_kernel<<<4096, 256, 0, stream>>>(x1, ln2w, ln2b, h2);
    gemm8<1><<<256, 512, 0, stream>>>(h2, W1_t, ffh, 4096, 4096, 1024);
    gemm_ks<2><<<dim3(32, 8), 512, 0, stream>>>(ffh, W2_t, out, x1, 4096, 1024, 4096);
}

// Round 17
// 209.707 us; speedup vs baseline: 1.0955x; 1.0340x over previous
//
#include <hip/hip_runtime.h>

// ---------------------------------------------------------------------------
// Transformer block forward on gfx950.  B=2 T=2048 C=1024 H=16 HS=64 FF=4096.
// All matmuls: f16 inputs, fp32 MFMA accumulation (16x16x32).
// R17 = R16 (best config, 216.8us) + dispatch consolidation: ln1 and all four
//   weight repacks merged into one uber_prep kernel (independent memory-bound
//   work now overlaps; 13 -> 9 dispatches).  Compute kernels unchanged.
// ---------------------------------------------------------------------------

typedef _Float16 f16;
typedef _Float16 f16x8 __attribute__((ext_vector_type(8)));
typedef _Float16 f16x4v __attribute__((ext_vector_type(4)));
typedef float f32x4 __attribute__((ext_vector_type(4)));

static constexpr int Tn = 2048;
static constexpr int Cn = 1024;
static constexpr int HSn = 64;

// async global->LDS, 16B per lane; dest = wave-uniform base + lane*16
__device__ __forceinline__ void glds16(const f16* g, f16* l) {
    __builtin_amdgcn_global_load_lds((const __attribute__((address_space(1))) void*)g,
                                     (__attribute__((address_space(3))) void*)l,
                                     16, 0, 0);
}

#define VMCNT(N) asm volatile("s_waitcnt vmcnt(" #N ")" ::: "memory")
// raw barrier with code-motion fences (no implicit vmcnt/lgkm drain)
__device__ __forceinline__ void barrier_raw() {
    asm volatile("" ::: "memory");
    __builtin_amdgcn_s_barrier();
    asm volatile("" ::: "memory");
}

// pack two f32 -> two f16 (RTZ) as a u32 (v_cvt_pkrtz_f16_f32)
__device__ __forceinline__ unsigned cvt_pk_u32(float a, float b) {
    auto v = __builtin_amdgcn_cvt_pkrtz(a, b);
    union { __fp16 h2 __attribute__((ext_vector_type(2))); unsigned u; } c;
    c.h2 = v;
    return c.u;
}

// ---------------------------------------------------------------------------
// Shared bodies for the prep work (verbatim logic from the R16 kernels).
// ---------------------------------------------------------------------------
__device__ __forceinline__ void ln_body(const float* __restrict__ xr,
                                        const float* __restrict__ w,
                                        const float* __restrict__ b,
                                        f16* __restrict__ outr) {
    int tid = threadIdx.x, l = tid & 63, wv = tid >> 6;
    float4 v = *(const float4*)(xr + tid * 4);
    float s = v.x + v.y + v.z + v.w;
    float sq = v.x * v.x + v.y * v.y + v.z * v.z + v.w * v.w;
#pragma unroll
    for (int off = 32; off > 0; off >>= 1) {
        s += __shfl_down(s, off);
        sq += __shfl_down(sq, off);
    }
    __shared__ float red[8];
    if (l == 0) { red[wv] = s; red[wv + 4] = sq; }
    __syncthreads();
    float ts = red[0] + red[1] + red[2] + red[3];
    float tq = red[4] + red[5] + red[6] + red[7];
    float mean = ts * (1.0f / Cn);
    float var = tq * (1.0f / Cn) - mean * mean;
    float rstd = rsqrtf(var + 1e-5f);
    float4 wv4 = *(const float4*)(w + tid * 4);
    float4 bv4 = *(const float4*)(b + tid * 4);
    f16x4v o;
    o[0] = (f16)((v.x - mean) * rstd * wv4.x + bv4.x);
    o[1] = (f16)((v.y - mean) * rstd * wv4.y + bv4.y);
    o[2] = (f16)((v.z - mean) * rstd * wv4.z + bv4.z);
    o[3] = (f16)((v.w - mean) * rstd * wv4.w + bv4.w);
    *(f16x4v*)(outr + tid * 4) = o;
}

// transpose+cast one 32x32 tile: out[c][r] = in[r][c]
__device__ __forceinline__ void tr_tile(const float* __restrict__ in, int irs,
                                        f16* __restrict__ out, int ors,
                                        int r0, int c0) {
    __shared__ float tile[32][33];
    int t = threadIdx.x;
    int rr = t >> 3, c4 = (t & 7) * 4;
    float4 v = *(const float4*)(in + (size_t)(r0 + rr) * irs + c0 + c4);
    tile[rr][c4] = v.x; tile[rr][c4 + 1] = v.y; tile[rr][c4 + 2] = v.z; tile[rr][c4 + 3] = v.w;
    __syncthreads();
    int cc = t >> 3, r4 = (t & 7) * 4;
    f16x4v o;
    o[0] = (f16)tile[r4][cc];
    o[1] = (f16)tile[r4 + 1][cc];
    o[2] = (f16)tile[r4 + 2][cc];
    o[3] = (f16)tile[r4 + 3][cc];
    *(f16x4v*)(out + (size_t)(c0 + cc) * ors + r0 + r4) = o;
}

// ---------------------------------------------------------------------------
// uber_prep: ln1 (4096 blocks) + Wqkv repack (3072) + Wproj (1024) +
// W1 (4096) + W2 (4096) in one dispatch = 16384 blocks, 256 threads.
// All parts independent (ln reads x; repacks read weights).
// ---------------------------------------------------------------------------
__global__ __launch_bounds__(256) void uber_prep(const float* __restrict__ x,
                                                 const float* __restrict__ ln1w,
                                                 const float* __restrict__ ln1b,
                                                 f16* __restrict__ h1,
                                                 const float* __restrict__ Wq,
                                                 const float* __restrict__ Wk,
                                                 const float* __restrict__ Wv,
                                                 f16* __restrict__ Wqkv_t,
                                                 const float* __restrict__ Wproj,
                                                 f16* __restrict__ Wproj_t,
                                                 const float* __restrict__ W1,
                                                 f16* __restrict__ W1_t,
                                                 const float* __restrict__ W2,
                                                 f16* __restrict__ W2_t) {
    int id = blockIdx.x;
    if (id < 4096) { // ln1 row
        ln_body(x + (size_t)id * Cn, ln1w, ln1b, h1 + (size_t)id * Cn);
        return;
    }
    id -= 4096;
    if (id < 3072) { // Wqkv repack: z = id/64 (qkv*16+h), tile = id%64 (x*2+y)
        int z = id >> 6, rest = id & 63;
        int xb = rest >> 1, yb = rest & 1; // x 0..31 (rows of C), y 0..1 (cols of HS)
        int qkv = z >> 4, h = z & 15;
        const float* in = (qkv == 0 ? Wq : qkv == 1 ? Wk : Wv) + (size_t)h * Cn * HSn;
        f16* o = Wqkv_t + (size_t)(qkv * Cn + h * HSn) * Cn;
        tr_tile(in, HSn, o, Cn, xb * 32, yb * 32);
        return;
    }
    id -= 3072;
    if (id < 1024) { // Wproj [1024][1024]: x = id&31, y = id>>5
        tr_tile(Wproj, 1024, Wproj_t, 1024, (id & 31) * 32, (id >> 5) * 32);
        return;
    }
    id -= 1024;
    if (id < 4096) { // W1 [1024][4096] -> W1_t [4096][1024]: x = id&31, y = id>>5
        tr_tile(W1, 4096, W1_t, 1024, (id & 31) * 32, (id >> 5) * 32);
        return;
    }
    id -= 4096;
    { // W2 [4096][1024] -> W2_t [1024][4096]: x = id&127, y = id>>7
        tr_tile(W2, 1024, W2_t, 4096, (id & 127) * 32, (id >> 7) * 32);
    }
}

// ---------------------------------------------------------------------------
// LayerNorm (fp32 in) -> f16 out.  One block per row, 256 threads.  (ln2)
// ---------------------------------------------------------------------------
__global__ __launch_bounds__(256) void ln_kernel(const float* __restrict__ x,
                                                 const float* __restrict__ w,
                                                 const float* __restrict__ b,
                                                 f16* __restrict__ out) {
    int row = blockIdx.x;
    ln_body(x + (size_t)row * Cn, w, b, out + (size_t)row * Cn);
}

// ---------------------------------------------------------------------------
// f16 transpose: vT[bh][s][t] = QKV[(b*T+t)][2048 + h*64 + s].  64x64 tiles.
// ---------------------------------------------------------------------------
__global__ __launch_bounds__(256) void tr_vT(const f16* __restrict__ QKV, f16* __restrict__ vT) {
    int bh = blockIdx.z;
    int b = bh >> 4, h = bh & 15;
    const f16* in = QKV + (size_t)b * Tn * 3072 + 2048 + h * HSn; // [T][64] stride 3072
    f16* out = vT + (size_t)bh * HSn * Tn;                        // [64][T]
    int r0 = blockIdx.x * 64;
    __shared__ __align__(16) f16 tile[64][72];
    int t = threadIdx.x;
#pragma unroll
    for (int i = 0; i < 2; i++) {
        int f = i * 256 + t;
        int rr = f >> 3, c8 = (f & 7) * 8;
        *(uint4*)(&tile[rr][c8]) = *(const uint4*)(in + (size_t)(r0 + rr) * 3072 + c8);
    }
    __syncthreads();
#pragma unroll
    for (int i = 0; i < 2; i++) {
        int f = i * 256 + t;
        int cc = f >> 3, r8 = (f & 7) * 8;
        union { f16 h[8]; uint4 v; } u;
#pragma unroll
        for (int j = 0; j < 8; j++) u.h[j] = tile[r8 + j][cc];
        *(uint4*)(out + (size_t)cc * Tn + r0 + r8) = u.v;
    }
}

// ---------------------------------------------------------------------------
// gemm8: C[M][N] = A[M][K] @ Bt[N][K]^T, 256x256 tile, 8 waves (2M x 4N),
// BK=32, 4 LDS buffers, stage depth 3, vmcnt(8)+s_barrier per K-tile,
// 2 phases x 16 MFMA, XOR chunk swizzle both sides, setprio.  (QKV, FF1)
// ---------------------------------------------------------------------------
template <int EPI>
__global__ __launch_bounds__(512, 2) void gemm8(const f16* __restrict__ A, const f16* __restrict__ Bt,
                                                f16* __restrict__ Cout, int M, int N, int K) {
    __shared__ __align__(16) f16 Abuf[4][8192];
    __shared__ __align__(16) f16 Bbuf[4][8192];
    int wg = blockIdx.x;
    int xcd = wg & 7, idx = wg >> 3;
    int bm = xcd * 2 + (idx & 1), bn = idx >> 1;
    int tid = threadIdx.x, l = tid & 63, w = tid >> 6;
    int wr = w >> 2, wc = w & 3;

    f32x4 acc[8][4];
#pragma unroll
    for (int m = 0; m < 8; m++)
#pragma unroll
        for (int n = 0; n < 4; n++) acc[m][n] = f32x4{0.f, 0.f, 0.f, 0.f};

    int l15 = l & 15;
    int lane_off = l15 * 32 + (((l >> 4) ^ ((l15 >> 1) & 3)) << 3);
    const f16* Afr = &Abuf[0][wr * 4096 + lane_off];
    const f16* Bfr = &Bbuf[0][(wc >> 1) * 4096 + (wc & 1) * 2048 + lane_off];

    int srow = w * 16 + (l >> 2);
    int schunk = (l & 3) ^ ((l >> 3) & 3);
    const f16* agp = A + (size_t)(bm * 256 + srow) * K + schunk * 8;
    const f16* bgp = Bt + (size_t)(bn * 256 + srow) * K + schunk * 8;
    const size_t rK = (size_t)128 * K;
    f16* dstA = &Abuf[0][w * 512];
    f16* dstB = &Bbuf[0][w * 512];

    auto stage = [&](int kt, int bf) {
        int k0 = kt * 32;
        glds16(agp + k0, dstA + bf * 8192);
        glds16(agp + rK + k0, dstA + bf * 8192 + 4096);
        glds16(bgp + k0, dstB + bf * 8192);
        glds16(bgp + rK + k0, dstB + bf * 8192 + 4096);
    };

    int NT = K >> 5;
    stage(0, 0);
    stage(1, 1);
    stage(2, 2);
    for (int t = 0; t < NT; ++t) {
        int cb = t & 3;
        VMCNT(8);
        barrier_raw();
        const f16* Ab = Afr + cb * 8192;
        const f16* Bb = Bfr + cb * 8192;
        f16x8 af[4], bf4[4];
#pragma unroll
        for (int m = 0; m < 4; m++) af[m] = *(const f16x8*)(Ab + m * 512);
#pragma unroll
        for (int n = 0; n < 4; n++) bf4[n] = *(const f16x8*)(Bb + n * 512);
        if (t + 3 < NT) stage(t + 3, (t + 3) & 3);
        __builtin_amdgcn_s_setprio(1);
#pragma unroll
        for (int m = 0; m < 4; m++)
#pragma unroll
            for (int n = 0; n < 4; n++)
                acc[m][n] = __builtin_amdgcn_mfma_f32_16x16x32_f16(af[m], bf4[n], acc[m][n], 0, 0, 0);
        __builtin_amdgcn_s_setprio(0);
        barrier_raw();
#pragma unroll
        for (int m = 0; m < 4; m++) af[m] = *(const f16x8*)(Ab + (m + 4) * 512);
        __builtin_amdgcn_s_setprio(1);
#pragma unroll
        for (int m = 0; m < 4; m++)
#pragma unroll
            for (int n = 0; n < 4; n++)
                acc[m + 4][n] = __builtin_amdgcn_mfma_f32_16x16x32_f16(af[m], bf4[n], acc[m + 4][n], 0, 0, 0);
        __builtin_amdgcn_s_setprio(0);
    }
    VMCNT(0);

    int row0 = bm * 256 + wr * 128 + (l >> 4) * 4;
    int col0 = bn * 256 + wc * 64 + (l & 15);
#pragma unroll
    for (int m = 0; m < 8; m++) {
#pragma unroll
        for (int n = 0; n < 4; n++) {
#pragma unroll
            for (int r = 0; r < 4; r++) {
                size_t idx = (size_t)(row0 + m * 16 + r) * N + (col0 + n * 16);
                float v = acc[m][n][r];
                if constexpr (EPI == 1) v = fmaxf(v, 0.f);
                Cout[idx] = (f16)v;
            }
        }
    }
}

// L2-aware decode for 128^2 grids: XCD x owns bm-chunk [4x, 4x+4).
__device__ __forceinline__ void l2_map(int& bm, int& bn) {
    int wg = blockIdx.y * 32 + blockIdx.x;
    int x = wg & 7, idx = wg >> 3;
    bm = x * 4 + (idx & 3);
    bn = idx >> 2;
}

// ---------------------------------------------------------------------------
// GEMM with in-block split-K + deep pipeline (3 buffers, vmcnt(4), raw
// barriers, XOR swizzle both sides).  Group 1 reduced into group 0 via LDS.
// (proj, FF2)
// ---------------------------------------------------------------------------
template <int EPI>
__global__ __launch_bounds__(512) void gemm_ks(const f16* __restrict__ A, const f16* __restrict__ Bt,
                                               void* __restrict__ Cout, const float* __restrict__ resid,
                                               int M, int N, int K) {
    __shared__ __align__(16) char smem[98304];
    f16* As = (f16*)smem;            // [grp][3][4096] = 48KB
    f16* Bs = (f16*)(smem + 49152);  // [grp][3][4096] = 48KB
    int bm, bn;
    l2_map(bm, bn);
    int tid = threadIdx.x, l = tid & 63, w = tid >> 6;
    int grp = w >> 2, wl = w & 3;
    int wr = wl >> 1, wc = wl & 1;
    int Kh = K >> 1;
    int KT = Kh >> 5;

    f32x4 acc[4][4];
#pragma unroll
    for (int m = 0; m < 4; m++)
#pragma unroll
        for (int n = 0; n < 4; n++) acc[m][n] = f32x4{0.f, 0.f, 0.f, 0.f};

    int schunk = (l & 3) ^ ((l >> 3) & 3);
    const f16* agp = A + (size_t)(bm * 128 + wl * 16 + (l >> 2)) * K + grp * Kh + schunk * 8;
    const f16* bgp = Bt + (size_t)(bn * 128 + wl * 16 + (l >> 2)) * K + grp * Kh + schunk * 8;
    const size_t half = (size_t)64 * K;
    f16* Ab = As + grp * 12288;
    f16* Bb = Bs + grp * 12288;

    auto stage = [&](int kt, int bf) {
        size_t k0 = (size_t)kt * 32;
        glds16(agp + k0, Ab + bf * 4096 + wl * 512);
        glds16(agp + half + k0, Ab + bf * 4096 + 2048 + wl * 512);
        glds16(bgp + k0, Bb + bf * 4096 + wl * 512);
        glds16(bgp + half + k0, Bb + bf * 4096 + 2048 + wl * 512);
    };

    int l15 = l & 15;
    int rbase = (wr * 64 + l15) * 32 + (((l >> 4) ^ ((l15 >> 1) & 3)) << 3);
    int cbase = (wc * 64 + l15) * 32 + (((l >> 4) ^ ((l15 >> 1) & 3)) << 3);

    stage(0, 0);
    if (KT > 1) stage(1, 1);
    int nb = 2;
    for (int kt = 0; kt < KT; ++kt) {
        int cb = kt % 3;
        if (kt + 1 < KT) VMCNT(4);
        else VMCNT(0);
        barrier_raw();
        if (kt + 2 < KT) { stage(kt + 2, nb); nb = (nb == 2) ? 0 : nb + 1; }
        f16x8 af[4], bfr[4];
#pragma unroll
        for (int m = 0; m < 4; m++) af[m] = *(const f16x8*)(Ab + cb * 4096 + rbase + m * 512);
#pragma unroll
        for (int n = 0; n < 4; n++) bfr[n] = *(const f16x8*)(Bb + cb * 4096 + cbase + n * 512);
        __builtin_amdgcn_s_setprio(1);
#pragma unroll
        for (int m = 0; m < 4; m++)
#pragma unroll
            for (int n = 0; n < 4; n++)
                acc[m][n] = __builtin_amdgcn_mfma_f32_16x16x32_f16(af[m], bfr[n], acc[m][n], 0, 0, 0);
        __builtin_amdgcn_s_setprio(0);
    }
    __syncthreads(); // all compute done (drains lgkm/vm) before red aliases As

    float* red = (float*)smem;
#pragma unroll
    for (int m = 0; m < 4; m++) {
        if (grp == 1) {
#pragma unroll
            for (int n = 0; n < 4; n++)
                *(f32x4*)(red + wl * 1280 + l * 20 + n * 4) = acc[m][n];
        }
        __syncthreads();
        if (grp == 0) {
#pragma unroll
            for (int n = 0; n < 4; n++)
                acc[m][n] += *(const f32x4*)(red + wl * 1280 + l * 20 + n * 4);
        }
        __syncthreads();
    }

    if (grp == 0) {
        int row0 = bm * 128 + wr * 64 + (l >> 4) * 4;
        int col0 = bn * 128 + wc * 64 + (l & 15);
#pragma unroll
        for (int m = 0; m < 4; m++) {
#pragma unroll
            for (int n = 0; n < 4; n++) {
#pragma unroll
                for (int r = 0; r < 4; r++) {
                    size_t idx = (size_t)(row0 + m * 16 + r) * N + (col0 + n * 16);
                    float v = acc[m][n][r];
                    if constexpr (EPI == 0) ((f16*)Cout)[idx] = (f16)v;
                    else if constexpr (EPI == 1) ((f16*)Cout)[idx] = (f16)fmaxf(v, 0.f);
                    else ((float*)Cout)[idx] = v + resid[idx];
                }
            }
        }
    }
}

// ---------------------------------------------------------------------------
// Flash attention, causal.  One q-tile per block, grid 1024 (3 blocks/CU,
// 42KB LDS), long-blocks-first dispatch, bh grouped per XCD.  Swapped QK^T,
// exp2-domain softmax, diagonal-only mask.  T14 reg-staged K/V; per-lane
// defer-max check with the cross-lane reduce inside the rare rescale branch.
// ---------------------------------------------------------------------------
__global__ __launch_bounds__(256) void attn_kernel(const f16* __restrict__ QKV,
                                                   const f16* __restrict__ vT,
                                                   const float* __restrict__ p,
                                                   f16* __restrict__ att) {
    int i = blockIdx.x;                      // 1024 = 8 xcd x 4 bh x 32 qt
    int bh = (i & 7) * 4 + ((i >> 3) & 3);   // XCD owns 4 heads (K/V L2-fit)
    int qt = 31 - (i >> 5);                  // low idx -> large qt (long first)
    int b = bh >> 4, h = bh & 15;
    int tid = threadIdx.x, w = tid >> 6, l = tid & 63;
    float sc2 = rsqrtf(p[h]) * 1.44269504f;  // scale * log2(e)

    __shared__ __align__(16) f16 Ks[2][4096];
    __shared__ __align__(16) f16 Vs[2][4096];
    __shared__ __align__(16) f16 Ps[4][16 * 80];
    f16* Pw = &Ps[w][0];

    int srow0 = tid >> 3;
    int c0 = (tid & 7) ^ (srow0 & 7);
    const f16* Kg = QKV + (size_t)b * Tn * 3072 + 1024 + h * HSn;
    const f16* Vg = vT + (size_t)bh * HSn * Tn;
    const f16* Kg0 = Kg + (size_t)srow0 * 3072 + c0 * 8;
    const f16* Kg1 = Kg + (size_t)(srow0 + 32) * 3072 + c0 * 8;
    const f16* Vg0 = Vg + (size_t)srow0 * Tn + c0 * 8;
    const f16* Vg1 = Vg + (size_t)(srow0 + 32) * Tn + c0 * 8;
    int dl = w * 512 + l * 8; // this thread's 16B LDS slot (f16 index)

    int foff[8];
#pragma unroll
    for (int n = 0; n < 4; n++)
#pragma unroll
        for (int ks = 0; ks < 2; ks++)
            foff[n * 2 + ks] = (n * 16 + (l & 15)) * 128 +
                               (((ks * 32 + (l >> 4) * 8) * 2) ^ ((l & 7) << 4));

    int qg = qt * 64 + w * 16 + (l & 15);
    int qo = qt * 64 + w * 16 + (l >> 4) * 4;
    const f16* qptr = QKV + (size_t)(b * Tn + qg) * 3072 + h * HSn + (l >> 4) * 8;
    f16x8 qf0 = *(const f16x8*)(qptr);
    f16x8 qf1 = *(const f16x8*)(qptr + 32);
    f16 sch = (f16)sc2;
#pragma unroll
    for (int j = 0; j < 8; j++) { qf0[j] *= sch; qf1[j] *= sch; }

    f32x4 o[4];
#pragma unroll
    for (int nf = 0; nf < 4; nf++) o[nf] = f32x4{0.f, 0.f, 0.f, 0.f};
    float m_r = -1e30f, l_r = 0.f; // lane-local l partial (reduced at end)

    int nt = qt + 1;
    uint4 kr0 = *(const uint4*)(Kg0);
    uint4 kr1 = *(const uint4*)(Kg1);
    uint4 vr0 = *(const uint4*)(Vg0);
    uint4 vr1 = *(const uint4*)(Vg1);
    *(uint4*)(&Ks[0][dl]) = kr0;
    *(uint4*)(&Ks[0][2048 + dl]) = kr1;
    *(uint4*)(&Vs[0][dl]) = vr0;
    *(uint4*)(&Vs[0][2048 + dl]) = vr1;
    __syncthreads();
    for (int t = 0; t < nt; ++t) {
        int kv0 = t * 64;
        if (t + 1 < nt) { // T14: issue next tile's loads; consumed at tile end
            size_t ko = (size_t)(kv0 + 64) * 3072;
            kr0 = *(const uint4*)(Kg0 + ko);
            kr1 = *(const uint4*)(Kg1 + ko);
            vr0 = *(const uint4*)(Vg0 + kv0 + 64);
            vr1 = *(const uint4*)(Vg1 + kv0 + 64);
        }
        const char* Kb = (const char*)&Ks[t & 1][0];
        const char* Vb = (const char*)&Vs[t & 1][0];
        f32x4 s[4];
#pragma unroll
        for (int n = 0; n < 4; n++) s[n] = f32x4{0.f, 0.f, 0.f, 0.f};
        __builtin_amdgcn_s_setprio(1);
#pragma unroll
        for (int n = 0; n < 4; n++)
#pragma unroll
            for (int ks = 0; ks < 2; ks++) {
                f16x8 kf = *(const f16x8*)(Kb + foff[n * 2 + ks]);
                s[n] = __builtin_amdgcn_mfma_f32_16x16x32_f16(kf, ks == 0 ? qf0 : qf1, s[n], 0, 0, 0);
            }
        __builtin_amdgcn_s_setprio(0);
        if (t == qt) { // mask only on the diagonal tile
            int rel = qg - kv0;
#pragma unroll
            for (int n = 0; n < 4; n++)
#pragma unroll
                for (int r = 0; r < 4; r++) {
                    int kvr = n * 16 + (l >> 4) * 4 + r;
                    if (kvr > rel) s[n][r] = -1e30f;
                }
        }
        // per-lane partial max; full row reduce only inside the rare branch
        float tmax = -1e30f;
#pragma unroll
        for (int n = 0; n < 4; n++)
#pragma unroll
            for (int r = 0; r < 4; r++) tmax = fmaxf(tmax, s[n][r]);
        float lmul = 1.f;
        if (__any(tmax > m_r + 8.f)) { // T13 defer-rescale (exp2 domain)
            float rmax = fmaxf(tmax, __shfl_xor(tmax, 16));
            rmax = fmaxf(rmax, __shfl_xor(rmax, 32));
            float mnew = fmaxf(m_r, rmax);
            lmul = exp2f(m_r - mnew);
            m_r = mnew;
            float ar[4];
#pragma unroll
            for (int r = 0; r < 4; r++) ar[r] = __shfl(lmul, (l >> 4) * 4 + r);
#pragma unroll
            for (int nf = 0; nf < 4; nf++)
#pragma unroll
                for (int r = 0; r < 4; r++) o[nf][r] *= ar[r];
        }
        float rsum = 0.f;
#pragma unroll
        for (int n = 0; n < 4; n++) {
            float e0 = exp2f(s[n][0] - m_r), e1 = exp2f(s[n][1] - m_r);
            float e2 = exp2f(s[n][2] - m_r), e3 = exp2f(s[n][3] - m_r);
            rsum += (e0 + e1) + (e2 + e3);
            union { unsigned u[2]; f16x4v h4; } u;
            u.u[0] = cvt_pk_u32(e0, e1);
            u.u[1] = cvt_pk_u32(e2, e3);
            *(f16x4v*)(&Pw[(l & 15) * 80 + n * 16 + (l >> 4) * 4]) = u.h4;
        }
        l_r = l_r * lmul + rsum; // lane-local; lmul is row-uniform -> exact
        f16x8 pa0 = *(const f16x8*)(&Pw[(l & 15) * 80 + (l >> 4) * 8]);
        f16x8 pa1 = *(const f16x8*)(&Pw[(l & 15) * 80 + 32 + (l >> 4) * 8]);
        __builtin_amdgcn_s_setprio(1);
#pragma unroll
        for (int nf = 0; nf < 4; nf++)
#pragma unroll
            for (int ks = 0; ks < 2; ks++) {
                f16x8 vf = *(const f16x8*)(Vb + foff[nf * 2 + ks]);
                o[nf] = __builtin_amdgcn_mfma_f32_16x16x32_f16(ks == 0 ? pa0 : pa1, vf, o[nf], 0, 0, 0);
            }
        __builtin_amdgcn_s_setprio(0);
        if (t + 1 < nt) { // write next tile to the other buffer (T14 late half)
            int nbf = (t + 1) & 1;
            *(uint4*)(&Ks[nbf][dl]) = kr0;
            *(uint4*)(&Ks[nbf][2048 + dl]) = kr1;
            *(uint4*)(&Vs[nbf][dl]) = vr0;
            *(uint4*)(&Vs[nbf][2048 + dl]) = vr1;
            __syncthreads(); // writes visible; also fences buf[t&1] reuse
        }
    }
    // deferred l reduce (row sum across the 4 lane-groups), then broadcast
    float lsum = l_r;
    lsum += __shfl_xor(lsum, 16);
    lsum += __shfl_xor(lsum, 32);
    float lro[4];
#pragma unroll
    for (int r = 0; r < 4; r++) lro[r] = __shfl(lsum, (l >> 4) * 4 + r);
#pragma unroll
    for (int nf = 0; nf < 4; nf++) {
#pragma unroll
        for (int r = 0; r < 4; r++) {
            float v = o[nf][r] / lro[r];
            att[(size_t)(b * Tn + qo + r) * Cn + h * HSn + nf * 16 + (l & 15)] = (f16)v;
        }
    }
}

// ---------------------------------------------------------------------------
extern "C" void kernel_launch(void* const* d_in, const int* in_sizes, int n_in,
                              void* d_out, int out_size, void* d_ws, size_t ws_size,
                              hipStream_t stream) {
    const float* x = (const float*)d_in[0];
    const float* Wq = (const float*)d_in[1];
    const float* Wk = (const float*)d_in[2];
    const float* Wv = (const float*)d_in[3];
    const float* p = (const float*)d_in[4];
    const float* Wproj = (const float*)d_in[5];
    const float* W1 = (const float*)d_in[6];
    const float* W2 = (const float*)d_in[7];
    const float* ln1w = (const float*)d_in[8];
    const float* ln1b = (const float*)d_in[9];
    const float* ln2w = (const float*)d_in[10];
    const float* ln2b = (const float*)d_in[11];

    char* ws = (char*)d_ws;
    const size_t MB = 1ull << 20;
    f16* Wqkv_t = (f16*)(ws + 0 * MB);   // [3072][1024]
    f16* Wproj_t = (f16*)(ws + 6 * MB);  // [1024][1024]
    f16* W1_t = (f16*)(ws + 8 * MB);     // [4096][1024]
    f16* W2_t = (f16*)(ws + 16 * MB);    // [1024][4096]
    float* x1 = (float*)(ws + 24 * MB);  // [4096][1024] f32
    f16* QKV = (f16*)(ws + 40 * MB);     // [4096][3072]
    f16* h1 = (f16*)(ws + 64 * MB);      // [4096][1024]
    f16* vTb = (f16*)(ws + 64 * MB);     // [32][64][2048] (reuses h1 slot)
    f16* attb = (f16*)(ws + 72 * MB);    // [4096][1024]
    f16* h2 = attb;                      // reuse (att dead after proj gemm)
    f16* ffh = QKV;                      // [4096][4096] spans 40M..72M
    float* out = (float*)d_out;

    // prep: ln1 + all four weight repacks in one dispatch
    uber_prep<<<16384, 256, 0, stream>>>(x, ln1w, ln1b, h1,
                                         Wq, Wk, Wv, Wqkv_t,
                                         Wproj, Wproj_t, W1, W1_t, W2, W2_t);

    // block forward
    gemm8<0><<<192, 512, 0, stream>>>(h1, Wqkv_t, QKV, 4096, 3072, 1024);
    tr_vT<<<dim3(32, 1, 32), 256, 0, stream>>>(QKV, vTb);
    attn_kernel<<<1024, 256, 0, stream>>>(QKV, vTb, p, attb);
    gemm_ks<2><<<dim3(32, 8), 512, 0, stream>>>(attb, Wproj_t, x1, x, 4096, 1024, 1024);
    ln_kernel<<<4096, 256, 0, stream>>>(x1, ln2w, ln2b, h2);
    gemm8<1><<<256, 512, 0, stream>>>(h2, W1_t, ffh, 4096, 4096, 1024);
    gemm_ks<2><<<dim3(32, 8), 512, 0, stream>>>(ffh, W2_t, out, x1, 4096, 1024, 4096);
}